// Round 3
// baseline (750.171 us; speedup 1.0000x reference)
//
#include <hip/hip_runtime.h>
#include <hip/hip_fp16.h>
#include <math.h>

// ---------------------------------------------------------------------------
// Net_37512244363273: 5-level edge-conditioned graph conv + voxel pooling + FC
// Round 18: algorithm-level deletion. R17 evidence: grid.sync costs ~150us on
// 8-XCD gfx950 (mega_k 2450us) -- cooperative fusion dead. R15/R16 evidence:
// the NB0 sort machine's kernels are each ~45us latency floors. So:
//  - L0 conv: NO sort. Per-edge global atomicAdd of 7 floats into S[65536][8]
//    (L2-resident, fire-and-forget), node-parallel finish. Kills cnt0/
//    colscan0/bktscan0/part0/conv0c and the 33MB pay2 round-trip.
//  - ALL pooling: fused into conv epilogues via order-preserving uint
//    atomicMax (monotone float<->uint transform) + atomicAdd pos/cnt into
//    raw[level] rows [CO max-enc | 3 possum | 1 cnt]. Next conv decodes
//    lazily in its LDS staging. Kills 5 pool dispatches + 5 cluster sorts.
//  - Seg machinery: only edge segs L2-4 remain (84 tiles); scanA/scanB gone
//    (each seg = one scan block); seg1 bucket totals via device atomics in
//    cnt1 so bktscan1 joins D2.
// Pipeline: memset | D1 edge0+cnt1+hstats+hist | D2 conv0pool0+colscan1+
// bktscan1+scanC+wstats | D3 part1+scatter | D4 bucket1 | D5 conv1+pool |
// D6-8 conv2-4+pool | D9 fc.  10 dispatches + memset.
// ---------------------------------------------------------------------------

#define TILES1 256                 // seg1 tiles (1024 edges each)
#define TSZ1   1024
#define NB1    512                 // seg1 buckets (dst>>5, 32 nodes each)

__device__ __forceinline__ float ftanh(float x) {
    float e = __expf(2.f * x);
    return 1.f - 2.f / (e + 1.f);
}

// order-preserving float<->uint (monotone): enables atomicMax-based fmax
__device__ __forceinline__ unsigned fenc(float f) {
    int b = __float_as_int(f);
    return (b < 0) ? ~(unsigned)b : ((unsigned)b | 0x80000000u);
}
__device__ __forceinline__ float fdec(unsigned u) {
    int b = (u & 0x80000000u) ? (int)(u & 0x7fffffffu) : ~(int)u;
    return __int_as_float(b);
}

// decode element i of a pooled raw row [CI-3 max-enc | 3 possum | 1 cnt]
__device__ __forceinline__ float row_val(const unsigned* __restrict__ row,
                                         int i, int CI) {
    float cn = __uint_as_float(row[CI]);
    if (i < CI - 3) return (cn == 0.f) ? 0.f : fdec(row[i]);
    return __uint_as_float(row[i]) / fmaxf(cn, 1.f);
}

struct Seg3 {                       // edge segs for levels 2,3,4
    const int* idx[3];
    int*       cnt[3];
    int*       rp [3];
    int*       out[3];
    int        n  [3];
    int        nb [3];
    int        tstart[4];
};

struct GA {
    // inputs
    const int *src0, *dst0; const float* ea0;
    const int *src1, *dst1; const float* ea1;
    const float *x0, *pos0;
    const int* cluster[5];
    const float *w1[5], *b1[5], *w2[5], *b2[5], *root[5], *bias[5];
    const int* srcE[3]; const float* eaE[3];
    const float *fc_w, *fc_b;
    // workspace
    float* S0;                      // [65536][8]: S0..S5, cnt, pad
    unsigned* raw[5];               // pooled rows: 16/24/32/40/48 words
    float* H; float* sq;
    int *M1, *M21, *bktTot, *bs1;
    float4 *pay1, *rec1; int* rp1;
    Seg3 sg;
    float* out;
    // hstats (levels 1-4)
    const float* hea[4]; int hE[4]; int hb0[5];
    int hsB, tiles;
};

// ---------------------------------------------------------------------------
// K1: edge0 (1024) | cnt1 (256) | hstats (170) | hist segs2-4 (84)
// ---------------------------------------------------------------------------
__global__ __launch_bounds__(256) void k1_fuseA(GA A)
{
    __shared__ int sh[NB1];
    int B = blockIdx.x, t = threadIdx.x;

    if (B < 1024) {                                // ---- edge0 ----
        float w1r[15], b1r[5];
        #pragma unroll
        for (int i = 0; i < 15; i++) w1r[i] = A.w1[0][i];
        #pragma unroll
        for (int i = 0; i < 5; i++)  b1r[i] = A.b1[0][i];
        float acc[20];
        #pragma unroll
        for (int i = 0; i < 20; i++) acc[i] = 0.f;
        int base = B * 1024 + t;
        #pragma unroll
        for (int it = 0; it < 4; it++) {
            int i = base + it * 256;
            int sv = A.src0[i], d = A.dst0[i];
            float e0 = A.ea0[i * 3], e1 = A.ea0[i * 3 + 1], e2 = A.ea0[i * 3 + 2];
            float h[5];
            #pragma unroll
            for (int k = 0; k < 5; k++)
                h[k] = ftanh(e0 * w1r[k] + e1 * w1r[5 + k] + e2 * w1r[10 + k] + b1r[k]);
            int p = 5;
            #pragma unroll
            for (int k = 0; k < 5; k++) {
                acc[k] += h[k];
                #pragma unroll
                for (int k2 = k; k2 < 5; k2++) acc[p++] += h[k] * h[k2];
            }
            float xv = A.x0[sv];
            float* Sr = A.S0 + (size_t)d * 8;
            atomicAdd(&Sr[0], xv);
            atomicAdd(&Sr[1], h[0] * xv);
            atomicAdd(&Sr[2], h[1] * xv);
            atomicAdd(&Sr[3], h[2] * xv);
            atomicAdd(&Sr[4], h[3] * xv);
            atomicAdd(&Sr[5], h[4] * xv);
            atomicAdd(&Sr[6], 1.f);
        }
        float* red = (float*)sh;
        int wid = t >> 6, lane = t & 63;
        #pragma unroll
        for (int v = 0; v < 20; v++) {
            float s = acc[v];
            #pragma unroll
            for (int o = 32; o; o >>= 1) s += __shfl_down(s, o);
            if (lane == 0) red[wid * 20 + v] = s;
        }
        __syncthreads();
        if (t < 20)
            atomicAdd(&A.H[t], red[t] + red[20 + t] + red[40 + t] + red[60 + t]);
        return;
    }
    B -= 1024;
    if (B < TILES1) {                              // ---- cnt1 (+bktTot) ----
        for (int u = t; u < NB1; u += 256) sh[u] = 0;
        __syncthreads();
        int base = B * TSZ1 + t;
        #pragma unroll
        for (int it = 0; it < 4; it++)
            atomicAdd(&sh[A.dst1[base + it * 256] >> 5], 1);
        __syncthreads();
        for (int u = t; u < NB1; u += 256) {
            int c = sh[u];
            A.M1[(size_t)B * NB1 + u] = c;
            if (c) atomicAdd(&A.bktTot[u], c);
        }
        return;
    }
    B -= TILES1;
    if (B < A.hsB) {                               // ---- hstats (L1-4) ----
        const int K = 8;
        int j = 0;
        while (j < 3 && B >= A.hb0[j + 1]) j++;
        int bloc = B - A.hb0[j];
        const float* ea = A.hea[j];
        const float* w1p = A.w1[j + 1];
        const float* b1p = A.b1[j + 1];
        float w1r[15], b1r[5];
        #pragma unroll
        for (int i = 0; i < 15; i++) w1r[i] = w1p[i];
        #pragma unroll
        for (int i = 0; i < 5; i++)  b1r[i] = b1p[i];
        float acc[20];
        #pragma unroll
        for (int i = 0; i < 20; i++) acc[i] = 0.f;
        int base = bloc * 256 * K + t;
        for (int it = 0; it < K; it++) {
            int e = base + it * 256;
            if (e < A.hE[j]) {
                float e0 = ea[e * 3], e1 = ea[e * 3 + 1], e2 = ea[e * 3 + 2];
                float h[5];
                #pragma unroll
                for (int k = 0; k < 5; k++)
                    h[k] = ftanh(e0 * w1r[k] + e1 * w1r[5 + k] + e2 * w1r[10 + k] + b1r[k]);
                int p = 5;
                #pragma unroll
                for (int k = 0; k < 5; k++) {
                    acc[k] += h[k];
                    #pragma unroll
                    for (int k2 = k; k2 < 5; k2++) acc[p++] += h[k] * h[k2];
                }
            }
        }
        float* red = (float*)sh;
        int wid = t >> 6, lane = t & 63;
        #pragma unroll
        for (int v = 0; v < 20; v++) {
            float s = acc[v];
            #pragma unroll
            for (int o = 32; o; o >>= 1) s += __shfl_down(s, o);
            if (lane == 0) red[wid * 20 + v] = s;
        }
        __syncthreads();
        if (t < 20)
            atomicAdd(&A.H[(j + 1) * 20 + t],
                      red[t] + red[20 + t] + red[40 + t] + red[60 + t]);
        return;
    }
    B -= A.hsB;
    {                                              // ---- hist (segs 0-2) ----
        int s = 0;
        while (s < 2 && B >= A.sg.tstart[s + 1]) s++;
        int i0 = (B - A.sg.tstart[s]) * 1024;
        const int* idx = A.sg.idx[s];
        int* cnt = A.sg.cnt[s];
        int n = A.sg.n[s];
        #pragma unroll
        for (int j = 0; j < 4; j++) {
            int i = i0 + j * 256 + t;
            if (i < n) atomicAdd(&cnt[idx[i]], 1);
        }
    }
}

// ---------------------------------------------------------------------------
// K2: conv0pool0 (256) | colscan1 (512) | bktscan1 (1) | scanC (3) | wstats (5)
// ---------------------------------------------------------------------------
__global__ __launch_bounds__(256) void k2_fuseB(GA A)
{
    __shared__ int sc[256];
    __shared__ float wsm[96];
    int B = blockIdx.x, t = threadIdx.x;

    if (B < 256) {                                 // ---- conv0pool0 ----
        if (t < 60) wsm[t] = A.w2[0][t];
        else if (t >= 64  && t < 76)  wsm[60 + t - 64]  = A.b2[0][t - 64];
        else if (t >= 128 && t < 140) wsm[72 + t - 128] = A.root[0][t - 128];
        else if (t >= 192 && t < 204) wsm[84 + t - 192] = A.bias[0][t - 192];
        __syncthreads();
        int v = B * 256 + t;
        const float* Sr = A.S0 + (size_t)v * 8;
        float s0 = Sr[0], s1 = Sr[1], s2 = Sr[2], s3 = Sr[3], s4 = Sr[4], s5 = Sr[5];
        float dg = Sr[6];
        float inv = 1.f / fmaxf(dg, 1.f);
        float xv = A.x0[v];
        int c = A.cluster[0][v];
        unsigned* orow = A.raw[0] + (size_t)c * 16;
        #pragma unroll
        for (int o = 0; o < 12; o++) {
            float m = (wsm[60 + o] * s0 + wsm[o] * s1 + wsm[12 + o] * s2 +
                       wsm[24 + o] * s3 + wsm[36 + o] * s4 + wsm[48 + o] * s5) * inv +
                      xv * wsm[72 + o] + wsm[84 + o];
            atomicMax(&orow[o], fenc(m));
        }
        atomicAdd((float*)&orow[12], A.pos0[v * 3]);
        atomicAdd((float*)&orow[13], A.pos0[v * 3 + 1]);
        atomicAdd((float*)&orow[14], A.pos0[v * 3 + 2]);
        atomicAdd((float*)&orow[15], 1.f);
        return;
    }
    B -= 256;
    if (B < NB1) {                                 // ---- colscan1 ----
        int v = A.M1[(size_t)t * NB1 + B];
        sc[t] = v;
        __syncthreads();
        for (int d = 1; d < 256; d <<= 1) {
            int u = (t >= d) ? sc[t - d] : 0;
            __syncthreads();
            sc[t] += u;
            __syncthreads();
        }
        A.M21[(size_t)t * NB1 + B] = sc[t] - v;
        return;
    }
    B -= NB1;
    if (B < 1) {                                   // ---- bktscan1 ----
        int a0 = A.bktTot[2 * t], a1 = A.bktTot[2 * t + 1];
        int ps = a0 + a1;
        sc[t] = ps;
        __syncthreads();
        for (int d = 1; d < 256; d <<= 1) {
            int u = (t >= d) ? sc[t - d] : 0;
            __syncthreads();
            sc[t] += u;
            __syncthreads();
        }
        int excl = sc[t] - ps;
        A.bs1[2 * t]     = excl;
        A.bs1[2 * t + 1] = excl + a0;
        if (t == 255) A.bs1[512] = sc[255];
        return;
    }
    B -= 1;
    if (B < 3) {                                   // ---- scanC (1 blk/seg) ----
        int s = B;
        int nb = A.sg.nb[s];
        const int* cnt = A.sg.cnt[s];
        int* rp = A.sg.rp[s];
        int i0 = t * 16;
        int v[16];
        int sum = 0;
        #pragma unroll
        for (int k = 0; k < 16; k++) {
            int i = i0 + k;
            v[k] = (i < nb) ? cnt[i] : 0;
            sum += v[k];
        }
        int acc = sum;
        sc[t] = acc;
        __syncthreads();
        for (int d = 1; d < 256; d <<= 1) {
            int t2 = (t >= d) ? sc[t - d] : 0;
            __syncthreads();
            acc += t2;
            sc[t] = acc;
            __syncthreads();
        }
        int running = acc - sum;
        #pragma unroll
        for (int k = 0; k < 16; k++) {
            int i = i0 + k;
            if (i < nb) rp[i] = running;
            running += v[k];
        }
        if (i0 + 16 == nb) rp[nb] = running;
        return;
    }
    B -= 3;
    {                                              // ---- wstats (wave 0) ----
        if (t >= 64) return;
        int l = B;
        const float* w2l = A.w2[l];
        const float* b2l = A.b2[l];
        static const int cicoA[5] = {12, 300, 644, 1116, 1716};
        int cico = cicoA[l];
        float d[21];
        #pragma unroll
        for (int i = 0; i < 21; i++) d[i] = 0.f;
        for (int u = t; u < cico; u += 64) {
            float b = b2l[u];
            float w[5];
            #pragma unroll
            for (int k = 0; k < 5; k++) w[k] = w2l[k * cico + u];
            int p = 0;
            #pragma unroll
            for (int k = 0; k < 5; k++) {
                #pragma unroll
                for (int k2 = k; k2 < 5; k2++) d[p++] += w[k] * w[k2];
            }
            #pragma unroll
            for (int k = 0; k < 5; k++) d[15 + k] += b * w[k];
            d[20] += b * b;
        }
        #pragma unroll
        for (int i = 0; i < 21; i++) {
            #pragma unroll
            for (int off = 32; off; off >>= 1) d[i] += __shfl_down(d[i], off);
        }
        if (t == 0) {
            static const int EA[5] = {1048576, 262144, 65536, 16384, 4096};
            const float* H1 = A.H + l * 20;
            const float* H2 = H1 + 5;
            float sq = (float)EA[l] * d[20];
            #pragma unroll
            for (int k = 0; k < 5; k++) sq += 2.f * d[15 + k] * H1[k];
            int p = 0;
            #pragma unroll
            for (int k = 0; k < 5; k++) {
                #pragma unroll
                for (int k2 = k; k2 < 5; k2++) {
                    sq += ((k == k2) ? 1.f : 2.f) * d[p] * H2[p];
                    p++;
                }
            }
            A.sq[l] = sq;
        }
    }
}

// ---------------------------------------------------------------------------
// K3: part1 (256) | scatter segs (84)
// ---------------------------------------------------------------------------
__global__ __launch_bounds__(256) void k3_fuseC(GA A)
{
    __shared__ int shi[NB1];
    int B = blockIdx.x, t = threadIdx.x;

    if (B < TILES1) {                              // ---- part1 ----
        int tile = B;
        for (int u = t; u < NB1; u += 256)
            shi[u] = A.bs1[u] + A.M21[(size_t)tile * NB1 + u];
        __syncthreads();
        int base = tile * TSZ1 + t;
        #pragma unroll
        for (int it = 0; it < 4; it++) {
            int i = base + it * 256;
            int d = A.dst1[i];
            int key = (d << 16) | A.src1[i];
            float e0 = A.ea1[i * 3], e1 = A.ea1[i * 3 + 1], e2 = A.ea1[i * 3 + 2];
            int ps = atomicAdd(&shi[d >> 5], 1);
            A.pay1[ps] = make_float4(__int_as_float(key), e0, e1, e2);
        }
        return;
    }
    B -= TILES1;
    {                                              // ---- scatter ----
        int s = 0;
        while (s < 2 && B >= A.sg.tstart[s + 1]) s++;
        int i0 = (B - A.sg.tstart[s]) * 1024;
        const int* idx = A.sg.idx[s];
        int* cnt = A.sg.cnt[s];
        const int* rp = A.sg.rp[s];
        int* out = A.sg.out[s];
        int n = A.sg.n[s];
        #pragma unroll
        for (int j = 0; j < 4; j++) {
            int i = i0 + j * 256 + t;
            if (i < n) {
                int d = idx[i];
                int p = atomicSub(&cnt[d], 1) - 1;
                out[rp[d] + p] = i;
            }
        }
    }
}

// ---------------------------------------------------------------------------
// K4: bucket1 (512): sort bucket's records by dst, emit rp1 + rec1
// ---------------------------------------------------------------------------
__global__ __launch_bounds__(256) void k4_bucket1(GA A)
{
    __shared__ int hist[32], cur[32];
    int b = blockIdx.x, t = threadIdx.x;
    int lo = A.bs1[b], hi = A.bs1[b + 1];
    int bin0 = b << 5;
    if (t < 32) hist[t] = 0;
    __syncthreads();
    const float* payw = (const float*)A.pay1;
    for (int j = lo + t; j < hi; j += 256) {
        int rel = (int)(__float_as_uint(payw[4 * j]) >> 16) - bin0;
        atomicAdd(&hist[rel], 1);
    }
    __syncthreads();
    if (t < 32) {
        int v = hist[t];
        int val = v;
        #pragma unroll
        for (int d = 1; d < 32; d <<= 1) {
            int u = __shfl_up(val, d);
            if (t >= d) val += u;
        }
        cur[t] = lo + val - v;
        A.rp1[bin0 + t] = lo + val - v;
        if (b == NB1 - 1 && t == 31) A.rp1[NB1 * 32] = hi;
    }
    __syncthreads();
    for (int j = lo + t; j < hi; j += 256) {
        float4 R = A.pay1[j];
        int rel = (int)(__float_as_uint(R.x) >> 16) - bin0;
        int p = atomicAdd(&cur[rel], 1);
        A.rec1[p] = R;
    }
}

// ---------------------------------------------------------------------------
// K5: conv1 (block/node, streams rec1) + fused pool epilogue into raw[1]
// ---------------------------------------------------------------------------
__global__ __launch_bounds__(256) void k5_conv1(GA A)
{
    constexpr int CI = 15, CO = 20, CH = 48, CICO = CI * CO, RL = 16, RN = 24;
    __shared__ float w1s[20];
    __shared__ float4 recb[CH];
    __shared__ int   svb[CH];
    __shared__ float hb[CH * 6];
    __shared__ float xs[CH * CI];
    __shared__ float Sx[6 * CI];
    __shared__ float xown[CI];

    int t = threadIdx.x, v = blockIdx.x;
    const unsigned* rin = A.raw[0];
    if (t < 20) w1s[t] = (t < 15) ? A.w1[1][t] : A.b1[1][t - 15];
    if (t < CI) xown[t] = row_val(rin + (size_t)v * RL, t, CI);
    int r0 = A.rp1[v], r1 = A.rp1[v + 1];
    int d = r1 - r0;
    float acc = 0.f;

    for (int c0 = r0; c0 < r1; c0 += CH) {
        int cn = min(CH, r1 - c0);
        if (t < cn) {
            float4 R = A.rec1[c0 + t];
            recb[t] = R;
            svb[t]  = (int)(__float_as_uint(R.x) & 0xffffu);
            hb[t * 6] = 1.f;
        }
        __syncthreads();
        if (t < cn * 5) {
            int j = t / 5, k = t % 5;
            float e0 = recb[j].y, e1 = recb[j].z, e2 = recb[j].w;
            hb[j * 6 + 1 + k] =
                ftanh(e0 * w1s[k] + e1 * w1s[5 + k] + e2 * w1s[10 + k] + w1s[15 + k]);
        }
        for (int u = t; u < cn * CI; u += 256) {
            int j = u / CI, i = u - j * CI;
            xs[u] = row_val(rin + (size_t)svb[j] * RL, i, CI);
        }
        __syncthreads();
        if (t < 6 * CI) {
            int i = t / 6, k6 = t - (t / 6) * 6;
            for (int j = 0; j < cn; j++)
                acc += hb[j * 6 + k6] * xs[j * CI + i];
        }
        __syncthreads();
    }

    if (t < 6 * CI) Sx[t] = acc;
    __syncthreads();

    if (t < CO) {
        float m = 0.f;
        const float* w2 = A.w2[1];
        const float* b2 = A.b2[1];
        for (int i = 0; i < CI; i++) {
            m += b2[i * CO + t] * Sx[i * 6];
            #pragma unroll
            for (int k = 0; k < 5; k++)
                m += w2[k * CICO + i * CO + t] * Sx[i * 6 + 1 + k];
        }
        m /= fmaxf((float)d, 1.f);
        for (int i = 0; i < CI; i++) m += xown[i] * A.root[1][i * CO + t];
        m += A.bias[1][t];
        int c = A.cluster[1][v];
        unsigned* orow = A.raw[1] + (size_t)c * RN;
        atomicMax(&orow[t], fenc(m));
        if (t < 3) atomicAdd((float*)&orow[CO + t], xown[CI - 3 + t]);
        if (t == 0) atomicAdd((float*)&orow[CO + 3], 1.f);
    }
}

// ---------------------------------------------------------------------------
// K6-8: coop conv levels 2-4 + fused pool epilogue
// ---------------------------------------------------------------------------
template<int CI, int CO>
__global__ __launch_bounds__(256) void coopP_k(GA A, int l)
{
    constexpr int CH = 48, CICO = CI * CO, RL = CI + 1, RN = CO + 4;
    __shared__ float w1s[20];
    __shared__ int   eb[CH], svb[CH];
    __shared__ float hb[CH * 6];
    __shared__ float xs[CH * CI];
    __shared__ float Sx[6 * CI];
    __shared__ float xown[CI];

    int t = threadIdx.x, v = blockIdx.x;
    int s = l - 2;
    const unsigned* rin = A.raw[l - 1];
    const int* rp = A.sg.rp[s];
    const int* eid = A.sg.out[s];
    const int* src = A.srcE[s];
    const float* eattr = A.eaE[s];

    if (t < 20) w1s[t] = (t < 15) ? A.w1[l][t] : A.b1[l][t - 15];
    if (t < CI) xown[t] = row_val(rin + (size_t)v * RL, t, CI);
    int r0 = rp[v], r1 = rp[v + 1];
    int d = r1 - r0;
    float acc = 0.f;

    for (int c0 = r0; c0 < r1; c0 += CH) {
        int cn = min(CH, r1 - c0);
        if (t < cn) {
            int e = eid[c0 + t];
            eb[t]  = e;
            svb[t] = src[e];
            hb[t * 6] = 1.f;
        }
        __syncthreads();
        if (t < cn * 5) {
            int j = t / 5, k = t % 5;
            int e = eb[j];
            float e0 = eattr[e * 3], e1 = eattr[e * 3 + 1], e2 = eattr[e * 3 + 2];
            hb[j * 6 + 1 + k] =
                ftanh(e0 * w1s[k] + e1 * w1s[5 + k] + e2 * w1s[10 + k] + w1s[15 + k]);
        }
        for (int u = t; u < cn * CI; u += 256) {
            int j = u / CI, i = u - j * CI;
            xs[u] = row_val(rin + (size_t)svb[j] * RL, i, CI);
        }
        __syncthreads();
        if (t < 6 * CI) {
            int i = t / 6, k6 = t - (t / 6) * 6;
            for (int j = 0; j < cn; j++)
                acc += hb[j * 6 + k6] * xs[j * CI + i];
        }
        __syncthreads();
    }

    if (t < 6 * CI) Sx[t] = acc;
    __syncthreads();

    if (t < CO) {
        float m = 0.f;
        const float* w2 = A.w2[l];
        const float* b2 = A.b2[l];
        for (int i = 0; i < CI; i++) {
            m += b2[i * CO + t] * Sx[i * 6];
            #pragma unroll
            for (int k = 0; k < 5; k++)
                m += w2[k * CICO + i * CO + t] * Sx[i * 6 + 1 + k];
        }
        m /= fmaxf((float)d, 1.f);
        for (int i = 0; i < CI; i++) m += xown[i] * A.root[l][i * CO + t];
        m += A.bias[l][t];
        int c = A.cluster[l][v];
        unsigned* orow = A.raw[l] + (size_t)c * RN;
        atomicMax(&orow[t], fenc(m));
        if (t < 3) atomicAdd((float*)&orow[CO + t], xown[CI - 3 + t]);
        if (t == 0) atomicAdd((float*)&orow[CO + 3], 1.f);
    }
}

// ---------------------------------------------------------------------------
// K9: fc (decodes raw[4])
// ---------------------------------------------------------------------------
__global__ __launch_bounds__(128) void k9_fc(GA A)
{
    __shared__ float feat[8 * 376];
    __shared__ float logit[80];
    __shared__ float roff[8];
    const unsigned* r5 = A.raw[4];
    for (int idx = threadIdx.x; idx < 64 * 47; idx += 128) {
        int n = idx / 47, i = idx - n * 47;
        int b = n >> 3, s = n & 7;
        feat[b * 376 + s * 47 + i] = row_val(r5 + (size_t)n * 48, i, 47);
    }
    __syncthreads();
    int t = threadIdx.x;
    if (t < 80) {
        int b = t / 10, j = t % 10;
        float acc = A.fc_b[j];
        for (int k = 0; k < 376; k++) acc += feat[b * 376 + k] * A.fc_w[k * 10 + j];
        logit[t] = acc;
    }
    __syncthreads();
    if (t < 8) {
        float m = -1e30f;
        for (int j = 0; j < 10; j++) m = fmaxf(m, logit[t * 10 + j]);
        float ssum = 0.f;
        for (int j = 0; j < 10; j++) ssum += expf(logit[t * 10 + j] - m);
        roff[t] = m + logf(ssum);
    }
    __syncthreads();
    if (t < 80) A.out[t] = logit[t] - roff[t / 10];
    if (t == 0) {
        const float* sq = A.sq;
        float closs = 0.f;
        closs += sq[0] * (1.0f / 12582912.0f);
        closs += sq[1] * (1.0f / 78643200.0f);
        closs += sq[2] * (1.0f / 42205184.0f);
        closs += sq[3] * (1.0f / 18284544.0f);
        closs += sq[4] * (1.0f / 7028736.0f);
        A.out[80] = closs;
    }
}

// ---------------------------------------------------------------------------

extern "C" void kernel_launch(void* const* d_in, const int* in_sizes, int n_in,
                              void* d_out, int out_size, void* d_ws, size_t ws_size,
                              hipStream_t stream)
{
    static const int NSa[6] = {65536, 16384, 4096, 1024, 256, 64};
    static const int ESa[5] = {1048576, 262144, 65536, 16384, 4096};
    static const int RNa[5] = {16, 24, 32, 40, 48};   // raw row widths (words)

    // ---- workspace layout (words) ----
    int* wsw = (int*)d_ws;
    size_t off = 0;
    auto alw = [&](size_t n) -> size_t {
        size_t p = off; off += (n + 63) & ~(size_t)63; return p;
    };
    // zeroed region
    size_t degO[5];
    for (int l = 2; l < 5; l++) degO[l] = alw(NSa[l]);
    size_t HO   = alw(100);
    size_t btO  = alw(NB1);
    size_t S0O  = alw((size_t)65536 * 8);
    size_t rawO[5];
    for (int l = 0; l < 5; l++) rawO[l] = alw((size_t)NSa[l + 1] * RNa[l]);
    size_t zeroWords = off;
    // non-zeroed
    size_t rpO[5], eidO[5];
    for (int l = 2; l < 5; l++) rpO[l]  = alw(NSa[l] + 1);
    for (int l = 2; l < 5; l++) eidO[l] = alw(ESa[l]);
    size_t M1O   = alw((size_t)TILES1 * NB1);
    size_t M21O  = alw((size_t)TILES1 * NB1);
    size_t bs1O  = alw(NB1 + 1);
    size_t pay1O = alw((size_t)ESa[1] * 4);
    size_t rec1O = alw((size_t)ESa[1] * 4);
    size_t rp1O  = alw(NSa[1] + 1);
    size_t sqO   = alw(8);

    GA A{};
    A.src0 = (const int*)d_in[2];  A.dst0 = (const int*)d_in[3];
    A.ea0  = (const float*)d_in[4];
    A.src1 = (const int*)d_in[12]; A.dst1 = (const int*)d_in[13];
    A.ea1  = (const float*)d_in[14];
    A.x0   = (const float*)d_in[0];
    A.pos0 = (const float*)d_in[1];
    for (int l = 0; l < 5; l++) {
        A.cluster[l] = (const int*)d_in[5 + 10 * l];
        A.w1[l]   = (const float*)d_in[6 + 10 * l];
        A.b1[l]   = (const float*)d_in[7 + 10 * l];
        A.w2[l]   = (const float*)d_in[8 + 10 * l];
        A.b2[l]   = (const float*)d_in[9 + 10 * l];
        A.root[l] = (const float*)d_in[10 + 10 * l];
        A.bias[l] = (const float*)d_in[11 + 10 * l];
    }
    for (int s = 0; s < 3; s++) {
        A.srcE[s] = (const int*)d_in[2 + 10 * (s + 2)];
        A.eaE[s]  = (const float*)d_in[4 + 10 * (s + 2)];
    }
    A.fc_w = (const float*)d_in[52];
    A.fc_b = (const float*)d_in[53];
    A.S0 = (float*)(wsw + S0O);
    for (int l = 0; l < 5; l++) A.raw[l] = (unsigned*)(wsw + rawO[l]);
    A.H  = (float*)(wsw + HO);
    A.sq = (float*)(wsw + sqO);
    A.M1 = wsw + M1O; A.M21 = wsw + M21O;
    A.bktTot = wsw + btO; A.bs1 = wsw + bs1O;
    A.pay1 = (float4*)(wsw + pay1O);
    A.rec1 = (float4*)(wsw + rec1O);
    A.rp1  = wsw + rp1O;
    A.out  = (float*)d_out;

    int tiles = 0;
    for (int s = 0; s < 3; s++) {
        int l = s + 2;
        A.sg.idx[s] = (const int*)d_in[3 + 10 * l];
        A.sg.cnt[s] = wsw + degO[l];
        A.sg.rp [s] = wsw + rpO[l];
        A.sg.out[s] = wsw + eidO[l];
        A.sg.n  [s] = ESa[l];
        A.sg.nb [s] = NSa[l];
        A.sg.tstart[s] = tiles;
        tiles += (ESa[l] + 1023) / 1024;
    }
    A.sg.tstart[3] = tiles;
    A.tiles = tiles;                                 // 84

    int hsB = 0;
    A.hb0[0] = 0;
    for (int j = 0; j < 4; j++) {
        A.hea[j] = (const float*)d_in[4 + 10 * (j + 1)];
        A.hE[j]  = ESa[j + 1];
        hsB += (ESa[j + 1] + 2047) / 2048;
        A.hb0[j + 1] = hsB;
    }
    A.hsB = hsB;                                     // 170

    hipMemsetAsync(d_ws, 0, zeroWords * 4, stream);

    k1_fuseA<<<1024 + TILES1 + hsB + tiles, 256, 0, stream>>>(A);   // 1534
    k2_fuseB<<<256 + NB1 + 1 + 3 + 5,       256, 0, stream>>>(A);   // 777
    k3_fuseC<<<TILES1 + tiles,              256, 0, stream>>>(A);   // 340
    k4_bucket1<<<NB1,                       256, 0, stream>>>(A);   // 512
    k5_conv1<<<NSa[1],                      256, 0, stream>>>(A);   // 16384
    coopP_k<23, 28><<<NSa[2],               256, 0, stream>>>(A, 2);
    coopP_k<31, 36><<<NSa[3],               256, 0, stream>>>(A, 3);
    coopP_k<39, 44><<<NSa[4],               256, 0, stream>>>(A, 4);
    k9_fc<<<1, 128, 0, stream>>>(A);
}

// Round 5
// 415.155 us; speedup vs baseline: 1.8070x; 1.8070x over previous
//
#include <hip/hip_runtime.h>
#include <hip/hip_fp16.h>
#include <math.h>

// ---------------------------------------------------------------------------
// Net_37512244363273: 5-level edge-conditioned graph conv + voxel pooling + FC
// Round 20 = Round 19 resubmit (R19 bench died in container acquisition, not
// in the kernel; source re-audited for OOB/hang: none found).
// Atomic-transaction budget. R18 evidence: 7.34M device atomics = 233MB
// write-through at 611 GB/s (k1 382us) -- device atomics are ~32B fabric RMWs
// at ~20G/s. Replace L0 per-edge atomics with reservation-append:
//  - part0: LDS hist over 1024 dst-buckets (64 nodes), ONE bcnt atomic per
//    touched bucket (~647/block, 0.66M total), append 16B (xv,h-f16) records
//    to pay2[bucket*1280 + slot]. 10x fewer device atomics.
//  - conv0c: 1024 blocks, stream own bucket's contiguous records, LDS-atomic
//    aggregate into nacc[7][64], write y0[65536][12] plain.
//  - pool0: explicit segment-max via cluster0 sort (joins seg machinery;
//    hist/scan/scatter ride in existing dispatches) -> xn0[16384][15] plain
//    floats (conv1 staging loses the fdec decode).
//  - L1-4 pooling stays fused atomicMax (only ~0.6M atomics total).
// Pipeline: memset | D1 part0+cnt1+hstats+hist | D2 conv0c+colscan1+bktscan1+
// scanC+wstats | D3 part1+scatter | D4 bucket1+pool0 | D5 conv1 | D6-8
// conv2-4 | D9 fc.  9 dispatches + memset.
// ---------------------------------------------------------------------------

#define TILES1 256                 // seg1 tiles (1024 edges each)
#define TSZ1   1024
#define NB1    512                 // seg1 buckets (dst>>5, 32 nodes each)
#define NBUK   1024                // L0 buckets (dst>>6, 64 nodes each)
#define CAP0   1280                // per-bucket record capacity (avg 1024 +8s)

__device__ __forceinline__ float ftanh(float x) {
    float e = __expf(2.f * x);
    return 1.f - 2.f / (e + 1.f);
}

// order-preserving float<->uint (monotone): enables atomicMax-based fmax
__device__ __forceinline__ unsigned fenc(float f) {
    int b = __float_as_int(f);
    return (b < 0) ? ~(unsigned)b : ((unsigned)b | 0x80000000u);
}
__device__ __forceinline__ float fdec(unsigned u) {
    int b = (u & 0x80000000u) ? (int)(u & 0x7fffffffu) : ~(int)u;
    return __int_as_float(b);
}

// decode element i of a pooled raw row [CI-3 max-enc | 3 possum | 1 cnt]
__device__ __forceinline__ float row_val(const unsigned* __restrict__ row,
                                         int i, int CI) {
    float cn = __uint_as_float(row[CI]);
    if (i < CI - 3) return (cn == 0.f) ? 0.f : fdec(row[i]);
    return __uint_as_float(row[i]) / fmaxf(cn, 1.f);
}

struct Seg4 {                       // edge segs L2-4 + cluster0 seg
    const int* idx[4];
    int*       cnt[4];
    int*       rp [4];
    int*       out[4];
    int        n  [4];
    int        nb [4];
    int        tstart[5];
};

struct GA {
    // inputs
    const int *src0, *dst0; const float* ea0;
    const int *src1, *dst1; const float* ea1;
    const float *x0, *pos0;
    const int* cluster[5];
    const float *w1[5], *b1[5], *w2[5], *b2[5], *root[5], *bias[5];
    const int* srcE[3]; const float* eaE[3];
    const float *fc_w, *fc_b;
    // workspace
    int* bcnt;                      // [NBUK] L0 bucket reservation counters
    float4* pay2;                   // [NBUK*CAP0] L0 records
    float* y0;                      // [65536][12]
    float* xn0;                     // [16384][15] pooled level-0 (plain)
    unsigned* raw[5];               // pooled rows for levels 1-4 (raw[0] unused)
    float* H; float* sq;
    int *M1, *M21, *bktTot, *bs1;
    float4 *pay1, *rec1; int* rp1;
    Seg4 sg;
    float* out;
    // hstats (levels 1-4)
    const float* hea[4]; int hE[4]; int hb0[5];
    int hsB;
};

// ---------------------------------------------------------------------------
// K1: part0-append (1024) | cnt1 (256) | hstats (170) | hist 4 segs (148)
// ---------------------------------------------------------------------------
__global__ __launch_bounds__(256) void k1_fuseA(GA A)
{
    __shared__ int sh[NBUK];
    int B = blockIdx.x, t = threadIdx.x;

    if (B < 1024) {                                // ---- part0-append ----
        for (int u = t; u < NBUK; u += 256) sh[u] = 0;
        __syncthreads();
        int base = B * 1024 + t;
        int dreg[4];
        #pragma unroll
        for (int it = 0; it < 4; it++) {
            dreg[it] = A.dst0[base + it * 256];
            atomicAdd(&sh[dreg[it] >> 6], 1);
        }
        __syncthreads();
        // reserve contiguous ranges; sh becomes within-bucket global cursor
        for (int u = t; u < NBUK; u += 256) {
            int c = sh[u];
            sh[u] = c ? atomicAdd(&A.bcnt[u], c) : 0;
        }
        __syncthreads();
        float w1r[15], b1r[5];
        #pragma unroll
        for (int i = 0; i < 15; i++) w1r[i] = A.w1[0][i];
        #pragma unroll
        for (int i = 0; i < 5; i++)  b1r[i] = A.b1[0][i];
        float acc[20];
        #pragma unroll
        for (int i = 0; i < 20; i++) acc[i] = 0.f;
        #pragma unroll
        for (int it = 0; it < 4; it++) {
            int i = base + it * 256;
            int d = dreg[it];
            int sv = A.src0[i];
            float e0 = A.ea0[i * 3], e1 = A.ea0[i * 3 + 1], e2 = A.ea0[i * 3 + 2];
            float h[5];
            #pragma unroll
            for (int k = 0; k < 5; k++)
                h[k] = ftanh(e0 * w1r[k] + e1 * w1r[5 + k] + e2 * w1r[10 + k] + b1r[k]);
            int p = 5;
            #pragma unroll
            for (int k = 0; k < 5; k++) {
                acc[k] += h[k];
                #pragma unroll
                for (int k2 = k; k2 < 5; k2++) acc[p++] += h[k] * h[k2];
            }
            float xv = A.x0[sv];
            union HU { __half2 h2; float f; } p01, p23;
            p01.h2 = __floats2half2_rn(h[0], h[1]);
            p23.h2 = __floats2half2_rn(h[2], h[3]);
            unsigned wbits = ((unsigned)d << 16) |
                             (unsigned)__half_as_ushort(__float2half_rn(h[4]));
            int bk = d >> 6;
            int ps = atomicAdd(&sh[bk], 1);
            if (ps < CAP0)
                A.pay2[(size_t)bk * CAP0 + ps] =
                    make_float4(xv, p01.f, p23.f, __uint_as_float(wbits));
        }
        __syncthreads();
        float* red = (float*)sh;
        int wid = t >> 6, lane = t & 63;
        #pragma unroll
        for (int v = 0; v < 20; v++) {
            float s = acc[v];
            #pragma unroll
            for (int o = 32; o; o >>= 1) s += __shfl_down(s, o);
            if (lane == 0) red[wid * 20 + v] = s;
        }
        __syncthreads();
        if (t < 20)
            atomicAdd(&A.H[t], red[t] + red[20 + t] + red[40 + t] + red[60 + t]);
        return;
    }
    B -= 1024;
    if (B < TILES1) {                              // ---- cnt1 (+bktTot) ----
        for (int u = t; u < NB1; u += 256) sh[u] = 0;
        __syncthreads();
        int base = B * TSZ1 + t;
        #pragma unroll
        for (int it = 0; it < 4; it++)
            atomicAdd(&sh[A.dst1[base + it * 256] >> 5], 1);
        __syncthreads();
        for (int u = t; u < NB1; u += 256) {
            int c = sh[u];
            A.M1[(size_t)B * NB1 + u] = c;
            if (c) atomicAdd(&A.bktTot[u], c);
        }
        return;
    }
    B -= TILES1;
    if (B < A.hsB) {                               // ---- hstats (L1-4) ----
        const int K = 8;
        int j = 0;
        while (j < 3 && B >= A.hb0[j + 1]) j++;
        int bloc = B - A.hb0[j];
        const float* ea = A.hea[j];
        const float* w1p = A.w1[j + 1];
        const float* b1p = A.b1[j + 1];
        float w1r[15], b1r[5];
        #pragma unroll
        for (int i = 0; i < 15; i++) w1r[i] = w1p[i];
        #pragma unroll
        for (int i = 0; i < 5; i++)  b1r[i] = b1p[i];
        float acc[20];
        #pragma unroll
        for (int i = 0; i < 20; i++) acc[i] = 0.f;
        int base = bloc * 256 * K + t;
        for (int it = 0; it < K; it++) {
            int e = base + it * 256;
            if (e < A.hE[j]) {
                float e0 = ea[e * 3], e1 = ea[e * 3 + 1], e2 = ea[e * 3 + 2];
                float h[5];
                #pragma unroll
                for (int k = 0; k < 5; k++)
                    h[k] = ftanh(e0 * w1r[k] + e1 * w1r[5 + k] + e2 * w1r[10 + k] + b1r[k]);
                int p = 5;
                #pragma unroll
                for (int k = 0; k < 5; k++) {
                    acc[k] += h[k];
                    #pragma unroll
                    for (int k2 = k; k2 < 5; k2++) acc[p++] += h[k] * h[k2];
                }
            }
        }
        float* red = (float*)sh;
        int wid = t >> 6, lane = t & 63;
        #pragma unroll
        for (int v = 0; v < 20; v++) {
            float s = acc[v];
            #pragma unroll
            for (int o = 32; o; o >>= 1) s += __shfl_down(s, o);
            if (lane == 0) red[wid * 20 + v] = s;
        }
        __syncthreads();
        if (t < 20)
            atomicAdd(&A.H[(j + 1) * 20 + t],
                      red[t] + red[20 + t] + red[40 + t] + red[60 + t]);
        return;
    }
    B -= A.hsB;
    {                                              // ---- hist (4 segs) ----
        int s = 0;
        while (s < 3 && B >= A.sg.tstart[s + 1]) s++;
        int i0 = (B - A.sg.tstart[s]) * 1024;
        const int* idx = A.sg.idx[s];
        int* cnt = A.sg.cnt[s];
        int n = A.sg.n[s];
        #pragma unroll
        for (int j = 0; j < 4; j++) {
            int i = i0 + j * 256 + t;
            if (i < n) atomicAdd(&cnt[idx[i]], 1);
        }
    }
}

// ---------------------------------------------------------------------------
// K2: conv0c (1024) | colscan1 (512) | bktscan1 (1) | scanC (4) | wstats (5)
// ---------------------------------------------------------------------------
__global__ __launch_bounds__(256) void k2_fuseB(GA A)
{
    __shared__ int sc[256];
    __shared__ float wsm[96];
    __shared__ float nacc[7 * 64];
    int B = blockIdx.x, t = threadIdx.x;

    if (B < NBUK) {                                // ---- conv0c ----
        if (t < 60) wsm[t] = A.w2[0][t];
        else if (t >= 64  && t < 76)  wsm[60 + t - 64]  = A.b2[0][t - 64];
        else if (t >= 128 && t < 140) wsm[72 + t - 128] = A.root[0][t - 128];
        else if (t >= 192 && t < 204) wsm[84 + t - 192] = A.bias[0][t - 192];
        for (int u = t; u < 7 * 64; u += 256) nacc[u] = 0.f;
        __syncthreads();

        int n = A.bcnt[B];
        if (n > CAP0) n = CAP0;
        size_t base = (size_t)B * CAP0;
        for (int j = t; j < n; j += 256) {
            float4 R = A.pay2[base + j];
            union HU { float f; __half2 h2; } a01, a23;
            a01.f = R.y; a23.f = R.z;
            unsigned wbits = __float_as_uint(R.w);
            int rel = (int)(wbits >> 16) & 63;
            float xv = R.x;
            atomicAdd(&nacc[rel], xv);
            atomicAdd(&nacc[64 + rel],  __low2float(a01.h2)  * xv);
            atomicAdd(&nacc[128 + rel], __high2float(a01.h2) * xv);
            atomicAdd(&nacc[192 + rel], __low2float(a23.h2)  * xv);
            atomicAdd(&nacc[256 + rel], __high2float(a23.h2) * xv);
            atomicAdd(&nacc[320 + rel],
                      __half2float(__ushort_as_half((unsigned short)(wbits & 0xffffu))) * xv);
            atomicAdd(&nacc[384 + rel], 1.f);
        }
        __syncthreads();

        int v0 = B << 6;
        for (int u = t; u < 64 * 12; u += 256) {
            int rel = u / 12, o = u - rel * 12;
            float dg = nacc[384 + rel];
            float inv = 1.f / fmaxf(dg, 1.f);
            float msg = wsm[60 + o] * nacc[rel] + wsm[o] * nacc[64 + rel] +
                        wsm[12 + o] * nacc[128 + rel] + wsm[24 + o] * nacc[192 + rel] +
                        wsm[36 + o] * nacc[256 + rel] + wsm[48 + o] * nacc[320 + rel];
            float xv = A.x0[v0 + rel];
            A.y0[(size_t)(v0 + rel) * 12 + o] =
                msg * inv + xv * wsm[72 + o] + wsm[84 + o];
        }
        return;
    }
    B -= NBUK;
    if (B < NB1) {                                 // ---- colscan1 ----
        int v = A.M1[(size_t)t * NB1 + B];
        sc[t] = v;
        __syncthreads();
        for (int d = 1; d < 256; d <<= 1) {
            int u = (t >= d) ? sc[t - d] : 0;
            __syncthreads();
            sc[t] += u;
            __syncthreads();
        }
        A.M21[(size_t)t * NB1 + B] = sc[t] - v;
        return;
    }
    B -= NB1;
    if (B < 1) {                                   // ---- bktscan1 ----
        int a0 = A.bktTot[2 * t], a1 = A.bktTot[2 * t + 1];
        int ps = a0 + a1;
        sc[t] = ps;
        __syncthreads();
        for (int d = 1; d < 256; d <<= 1) {
            int u = (t >= d) ? sc[t - d] : 0;
            __syncthreads();
            sc[t] += u;
            __syncthreads();
        }
        int excl = sc[t] - ps;
        A.bs1[2 * t]     = excl;
        A.bs1[2 * t + 1] = excl + a0;
        if (t == 255) A.bs1[512] = sc[255];
        return;
    }
    B -= 1;
    if (B < 4) {                                   // ---- scanC (1 blk/seg) ----
        int s = B;
        int nb = A.sg.nb[s];
        const int* cnt = A.sg.cnt[s];
        int* rp = A.sg.rp[s];
        int VPT = nb >> 8;
        int i0 = t * VPT;
        int sum = 0;
        for (int k = 0; k < VPT; k++) sum += cnt[i0 + k];
        int acc = sum;
        sc[t] = acc;
        __syncthreads();
        for (int d = 1; d < 256; d <<= 1) {
            int t2 = (t >= d) ? sc[t - d] : 0;
            __syncthreads();
            acc += t2;
            sc[t] = acc;
            __syncthreads();
        }
        int running = acc - sum;
        for (int k = 0; k < VPT; k++) {
            rp[i0 + k] = running;
            running += cnt[i0 + k];
        }
        if (t == 255) rp[nb] = running;
        return;
    }
    B -= 4;
    {                                              // ---- wstats (wave 0) ----
        if (t >= 64) return;
        int l = B;
        const float* w2l = A.w2[l];
        const float* b2l = A.b2[l];
        static const int cicoA[5] = {12, 300, 644, 1116, 1716};
        int cico = cicoA[l];
        float d[21];
        #pragma unroll
        for (int i = 0; i < 21; i++) d[i] = 0.f;
        for (int u = t; u < cico; u += 64) {
            float b = b2l[u];
            float w[5];
            #pragma unroll
            for (int k = 0; k < 5; k++) w[k] = w2l[k * cico + u];
            int p = 0;
            #pragma unroll
            for (int k = 0; k < 5; k++) {
                #pragma unroll
                for (int k2 = k; k2 < 5; k2++) d[p++] += w[k] * w[k2];
            }
            #pragma unroll
            for (int k = 0; k < 5; k++) d[15 + k] += b * w[k];
            d[20] += b * b;
        }
        #pragma unroll
        for (int i = 0; i < 21; i++) {
            #pragma unroll
            for (int off = 32; off; off >>= 1) d[i] += __shfl_down(d[i], off);
        }
        if (t == 0) {
            static const int EA[5] = {1048576, 262144, 65536, 16384, 4096};
            const float* H1 = A.H + l * 20;
            const float* H2 = H1 + 5;
            float sq = (float)EA[l] * d[20];
            #pragma unroll
            for (int k = 0; k < 5; k++) sq += 2.f * d[15 + k] * H1[k];
            int p = 0;
            #pragma unroll
            for (int k = 0; k < 5; k++) {
                #pragma unroll
                for (int k2 = k; k2 < 5; k2++) {
                    sq += ((k == k2) ? 1.f : 2.f) * d[p] * H2[p];
                    p++;
                }
            }
            A.sq[l] = sq;
        }
    }
}

// ---------------------------------------------------------------------------
// K3: part1 (256) | scatter 4 segs (148)
// ---------------------------------------------------------------------------
__global__ __launch_bounds__(256) void k3_fuseC(GA A)
{
    __shared__ int shi[NB1];
    int B = blockIdx.x, t = threadIdx.x;

    if (B < TILES1) {                              // ---- part1 ----
        int tile = B;
        for (int u = t; u < NB1; u += 256)
            shi[u] = A.bs1[u] + A.M21[(size_t)tile * NB1 + u];
        __syncthreads();
        int base = tile * TSZ1 + t;
        #pragma unroll
        for (int it = 0; it < 4; it++) {
            int i = base + it * 256;
            int d = A.dst1[i];
            int key = (d << 16) | A.src1[i];
            float e0 = A.ea1[i * 3], e1 = A.ea1[i * 3 + 1], e2 = A.ea1[i * 3 + 2];
            int ps = atomicAdd(&shi[d >> 5], 1);
            A.pay1[ps] = make_float4(__int_as_float(key), e0, e1, e2);
        }
        return;
    }
    B -= TILES1;
    {                                              // ---- scatter ----
        int s = 0;
        while (s < 3 && B >= A.sg.tstart[s + 1]) s++;
        int i0 = (B - A.sg.tstart[s]) * 1024;
        const int* idx = A.sg.idx[s];
        int* cnt = A.sg.cnt[s];
        const int* rp = A.sg.rp[s];
        int* out = A.sg.out[s];
        int n = A.sg.n[s];
        #pragma unroll
        for (int j = 0; j < 4; j++) {
            int i = i0 + j * 256 + t;
            if (i < n) {
                int d = idx[i];
                int p = atomicSub(&cnt[d], 1) - 1;
                out[rp[d] + p] = i;
            }
        }
    }
}

// ---------------------------------------------------------------------------
// K4: bucket1 (512) | pool0 (960)
// ---------------------------------------------------------------------------
__global__ __launch_bounds__(256) void k4_fuseD(GA A)
{
    __shared__ int hist[32], cur[32];
    int B = blockIdx.x, t = threadIdx.x;

    if (B < NB1) {                                 // ---- bucket1 ----
        int b = B;
        int lo = A.bs1[b], hi = A.bs1[b + 1];
        int bin0 = b << 5;
        if (t < 32) hist[t] = 0;
        __syncthreads();
        const float* payw = (const float*)A.pay1;
        for (int j = lo + t; j < hi; j += 256) {
            int rel = (int)(__float_as_uint(payw[4 * j]) >> 16) - bin0;
            atomicAdd(&hist[rel], 1);
        }
        __syncthreads();
        if (t < 32) {
            int v = hist[t];
            int val = v;
            #pragma unroll
            for (int d = 1; d < 32; d <<= 1) {
                int u = __shfl_up(val, d);
                if (t >= d) val += u;
            }
            cur[t] = lo + val - v;
            A.rp1[bin0 + t] = lo + val - v;
            if (b == NB1 - 1 && t == 31) A.rp1[NB1 * 32] = hi;
        }
        __syncthreads();
        for (int j = lo + t; j < hi; j += 256) {
            float4 R = A.pay1[j];
            int rel = (int)(__float_as_uint(R.x) >> 16) - bin0;
            int p = atomicAdd(&cur[rel], 1);
            A.rec1[p] = R;
        }
        return;
    }
    B -= NB1;
    {                                              // ---- pool0 ----
        int gt = B * 256 + t;
        if (gt >= 16384 * 15) return;
        int c = gt / 15, o = gt - c * 15;
        int r0 = A.sg.rp[3][c], r1 = A.sg.rp[3][c + 1];
        const int* cnid = A.sg.out[3];
        int d = r1 - r0;
        if (o < 12) {
            float m = -INFINITY;
            for (int j = r0; j < r1; j++)
                m = fmaxf(m, A.y0[(size_t)cnid[j] * 12 + o]);
            if (d == 0 || !isfinite(m)) m = 0.f;
            A.xn0[c * 15 + o] = m;
        } else {
            int k = o - 12;
            float sum = 0.f;
            for (int j = r0; j < r1; j++)
                sum += A.pos0[cnid[j] * 3 + k];
            A.xn0[c * 15 + o] = sum / fmaxf((float)d, 1.f);
        }
    }
}

// ---------------------------------------------------------------------------
// K5: conv1 (block/node, streams rec1, plain xn0 input) + pool->raw1
// ---------------------------------------------------------------------------
__global__ __launch_bounds__(256) void k5_conv1(GA A)
{
    constexpr int CI = 15, CO = 20, CH = 48, CICO = CI * CO, RN = 24;
    __shared__ float w1s[20];
    __shared__ float4 recb[CH];
    __shared__ int   svb[CH];
    __shared__ float hb[CH * 6];
    __shared__ float xs[CH * CI];
    __shared__ float Sx[6 * CI];
    __shared__ float xown[CI];

    int t = threadIdx.x, v = blockIdx.x;
    if (t < 20) w1s[t] = (t < 15) ? A.w1[1][t] : A.b1[1][t - 15];
    if (t < CI) xown[t] = A.xn0[v * CI + t];
    int r0 = A.rp1[v], r1 = A.rp1[v + 1];
    int d = r1 - r0;
    float acc = 0.f;

    for (int c0 = r0; c0 < r1; c0 += CH) {
        int cn = min(CH, r1 - c0);
        if (t < cn) {
            float4 R = A.rec1[c0 + t];
            recb[t] = R;
            svb[t]  = (int)(__float_as_uint(R.x) & 0xffffu);
            hb[t * 6] = 1.f;
        }
        __syncthreads();
        if (t < cn * 5) {
            int j = t / 5, k = t % 5;
            float e0 = recb[j].y, e1 = recb[j].z, e2 = recb[j].w;
            hb[j * 6 + 1 + k] =
                ftanh(e0 * w1s[k] + e1 * w1s[5 + k] + e2 * w1s[10 + k] + w1s[15 + k]);
        }
        for (int u = t; u < cn * CI; u += 256) {
            int j = u / CI, i = u - j * CI;
            xs[u] = A.xn0[svb[j] * CI + i];
        }
        __syncthreads();
        if (t < 6 * CI) {
            int i = t / 6, k6 = t - (t / 6) * 6;
            for (int j = 0; j < cn; j++)
                acc += hb[j * 6 + k6] * xs[j * CI + i];
        }
        __syncthreads();
    }

    if (t < 6 * CI) Sx[t] = acc;
    __syncthreads();

    if (t < CO) {
        float m = 0.f;
        const float* w2 = A.w2[1];
        const float* b2 = A.b2[1];
        for (int i = 0; i < CI; i++) {
            m += b2[i * CO + t] * Sx[i * 6];
            #pragma unroll
            for (int k = 0; k < 5; k++)
                m += w2[k * CICO + i * CO + t] * Sx[i * 6 + 1 + k];
        }
        m /= fmaxf((float)d, 1.f);
        for (int i = 0; i < CI; i++) m += xown[i] * A.root[1][i * CO + t];
        m += A.bias[1][t];
        int c = A.cluster[1][v];
        unsigned* orow = A.raw[1] + (size_t)c * RN;
        atomicMax(&orow[t], fenc(m));
        if (t < 3) atomicAdd((float*)&orow[CO + t], xown[CI - 3 + t]);
        if (t == 0) atomicAdd((float*)&orow[CO + 3], 1.f);
    }
}

// ---------------------------------------------------------------------------
// K6-8: coop conv levels 2-4 + fused pool epilogue
// ---------------------------------------------------------------------------
template<int CI, int CO>
__global__ __launch_bounds__(256) void coopP_k(GA A, int l)
{
    constexpr int CH = 48, CICO = CI * CO, RL = CI + 1, RN = CO + 4;
    __shared__ float w1s[20];
    __shared__ int   eb[CH], svb[CH];
    __shared__ float hb[CH * 6];
    __shared__ float xs[CH * CI];
    __shared__ float Sx[6 * CI];
    __shared__ float xown[CI];

    int t = threadIdx.x, v = blockIdx.x;
    int s = l - 2;
    const unsigned* rin = A.raw[l - 1];
    const int* rp = A.sg.rp[s];
    const int* eid = A.sg.out[s];
    const int* src = A.srcE[s];
    const float* eattr = A.eaE[s];

    if (t < 20) w1s[t] = (t < 15) ? A.w1[l][t] : A.b1[l][t - 15];
    if (t < CI) xown[t] = row_val(rin + (size_t)v * RL, t, CI);
    int r0 = rp[v], r1 = rp[v + 1];
    int d = r1 - r0;
    float acc = 0.f;

    for (int c0 = r0; c0 < r1; c0 += CH) {
        int cn = min(CH, r1 - c0);
        if (t < cn) {
            int e = eid[c0 + t];
            eb[t]  = e;
            svb[t] = src[e];
            hb[t * 6] = 1.f;
        }
        __syncthreads();
        if (t < cn * 5) {
            int j = t / 5, k = t % 5;
            int e = eb[j];
            float e0 = eattr[e * 3], e1 = eattr[e * 3 + 1], e2 = eattr[e * 3 + 2];
            hb[j * 6 + 1 + k] =
                ftanh(e0 * w1s[k] + e1 * w1s[5 + k] + e2 * w1s[10 + k] + w1s[15 + k]);
        }
        for (int u = t; u < cn * CI; u += 256) {
            int j = u / CI, i = u - j * CI;
            xs[u] = row_val(rin + (size_t)svb[j] * RL, i, CI);
        }
        __syncthreads();
        if (t < 6 * CI) {
            int i = t / 6, k6 = t - (t / 6) * 6;
            for (int j = 0; j < cn; j++)
                acc += hb[j * 6 + k6] * xs[j * CI + i];
        }
        __syncthreads();
    }

    if (t < 6 * CI) Sx[t] = acc;
    __syncthreads();

    if (t < CO) {
        float m = 0.f;
        const float* w2 = A.w2[l];
        const float* b2 = A.b2[l];
        for (int i = 0; i < CI; i++) {
            m += b2[i * CO + t] * Sx[i * 6];
            #pragma unroll
            for (int k = 0; k < 5; k++)
                m += w2[k * CICO + i * CO + t] * Sx[i * 6 + 1 + k];
        }
        m /= fmaxf((float)d, 1.f);
        for (int i = 0; i < CI; i++) m += xown[i] * A.root[l][i * CO + t];
        m += A.bias[l][t];
        int c = A.cluster[l][v];
        unsigned* orow = A.raw[l] + (size_t)c * RN;
        atomicMax(&orow[t], fenc(m));
        if (t < 3) atomicAdd((float*)&orow[CO + t], xown[CI - 3 + t]);
        if (t == 0) atomicAdd((float*)&orow[CO + 3], 1.f);
    }
}

// ---------------------------------------------------------------------------
// K9: fc (decodes raw[4])
// ---------------------------------------------------------------------------
__global__ __launch_bounds__(128) void k9_fc(GA A)
{
    __shared__ float feat[8 * 376];
    __shared__ float logit[80];
    __shared__ float roff[8];
    const unsigned* r5 = A.raw[4];
    for (int idx = threadIdx.x; idx < 64 * 47; idx += 128) {
        int n = idx / 47, i = idx - n * 47;
        int b = n >> 3, s = n & 7;
        feat[b * 376 + s * 47 + i] = row_val(r5 + (size_t)n * 48, i, 47);
    }
    __syncthreads();
    int t = threadIdx.x;
    if (t < 80) {
        int b = t / 10, j = t % 10;
        float acc = A.fc_b[j];
        for (int k = 0; k < 376; k++) acc += feat[b * 376 + k] * A.fc_w[k * 10 + j];
        logit[t] = acc;
    }
    __syncthreads();
    if (t < 8) {
        float m = -1e30f;
        for (int j = 0; j < 10; j++) m = fmaxf(m, logit[t * 10 + j]);
        float ssum = 0.f;
        for (int j = 0; j < 10; j++) ssum += expf(logit[t * 10 + j] - m);
        roff[t] = m + logf(ssum);
    }
    __syncthreads();
    if (t < 80) A.out[t] = logit[t] - roff[t / 10];
    if (t == 0) {
        const float* sq = A.sq;
        float closs = 0.f;
        closs += sq[0] * (1.0f / 12582912.0f);
        closs += sq[1] * (1.0f / 78643200.0f);
        closs += sq[2] * (1.0f / 42205184.0f);
        closs += sq[3] * (1.0f / 18284544.0f);
        closs += sq[4] * (1.0f / 7028736.0f);
        A.out[80] = closs;
    }
}

// ---------------------------------------------------------------------------

extern "C" void kernel_launch(void* const* d_in, const int* in_sizes, int n_in,
                              void* d_out, int out_size, void* d_ws, size_t ws_size,
                              hipStream_t stream)
{
    static const int NSa[6] = {65536, 16384, 4096, 1024, 256, 64};
    static const int ESa[5] = {1048576, 262144, 65536, 16384, 4096};
    static const int RNa[5] = {16, 24, 32, 40, 48};   // raw row widths (words)

    // ---- workspace layout (words) ----
    int* wsw = (int*)d_ws;
    size_t off = 0;
    auto alw = [&](size_t n) -> size_t {
        size_t p = off; off += (n + 63) & ~(size_t)63; return p;
    };
    // zeroed region
    size_t degO[5];
    for (int l = 2; l < 5; l++) degO[l] = alw(NSa[l]);
    size_t cdeg0O = alw(NSa[1]);                      // cluster0 counts (16384)
    size_t HO   = alw(100);
    size_t bcO  = alw(NBUK);
    size_t btO  = alw(NB1);
    size_t rawO[5];
    for (int l = 1; l < 5; l++) rawO[l] = alw((size_t)NSa[l + 1] * RNa[l]);
    size_t zeroWords = off;
    // non-zeroed
    size_t rpO[5], eidO[5];
    for (int l = 2; l < 5; l++) rpO[l]  = alw(NSa[l] + 1);
    size_t crp0O = alw(NSa[1] + 1);
    for (int l = 2; l < 5; l++) eidO[l] = alw(ESa[l]);
    size_t cnid0O = alw(NSa[0]);
    size_t pay2O = alw((size_t)NBUK * CAP0 * 4);
    size_t y0O   = alw((size_t)NSa[0] * 12);
    size_t xn0O  = alw((size_t)NSa[1] * 15);
    size_t M1O   = alw((size_t)TILES1 * NB1);
    size_t M21O  = alw((size_t)TILES1 * NB1);
    size_t bs1O  = alw(NB1 + 1);
    size_t pay1O = alw((size_t)ESa[1] * 4);
    size_t rec1O = alw((size_t)ESa[1] * 4);
    size_t rp1O  = alw(NSa[1] + 1);
    size_t sqO   = alw(8);

    GA A{};
    A.src0 = (const int*)d_in[2];  A.dst0 = (const int*)d_in[3];
    A.ea0  = (const float*)d_in[4];
    A.src1 = (const int*)d_in[12]; A.dst1 = (const int*)d_in[13];
    A.ea1  = (const float*)d_in[14];
    A.x0   = (const float*)d_in[0];
    A.pos0 = (const float*)d_in[1];
    for (int l = 0; l < 5; l++) {
        A.cluster[l] = (const int*)d_in[5 + 10 * l];
        A.w1[l]   = (const float*)d_in[6 + 10 * l];
        A.b1[l]   = (const float*)d_in[7 + 10 * l];
        A.w2[l]   = (const float*)d_in[8 + 10 * l];
        A.b2[l]   = (const float*)d_in[9 + 10 * l];
        A.root[l] = (const float*)d_in[10 + 10 * l];
        A.bias[l] = (const float*)d_in[11 + 10 * l];
    }
    for (int s = 0; s < 3; s++) {
        A.srcE[s] = (const int*)d_in[2 + 10 * (s + 2)];
        A.eaE[s]  = (const float*)d_in[4 + 10 * (s + 2)];
    }
    A.fc_w = (const float*)d_in[52];
    A.fc_b = (const float*)d_in[53];
    A.bcnt = wsw + bcO;
    A.pay2 = (float4*)(wsw + pay2O);
    A.y0   = (float*)(wsw + y0O);
    A.xn0  = (float*)(wsw + xn0O);
    for (int l = 1; l < 5; l++) A.raw[l] = (unsigned*)(wsw + rawO[l]);
    A.H  = (float*)(wsw + HO);
    A.sq = (float*)(wsw + sqO);
    A.M1 = wsw + M1O; A.M21 = wsw + M21O;
    A.bktTot = wsw + btO; A.bs1 = wsw + bs1O;
    A.pay1 = (float4*)(wsw + pay1O);
    A.rec1 = (float4*)(wsw + rec1O);
    A.rp1  = wsw + rp1O;
    A.out  = (float*)d_out;

    // seg descriptors: 0-2 = edge segs L2-4, 3 = cluster0
    int tiles = 0;
    for (int s = 0; s < 3; s++) {
        int l = s + 2;
        A.sg.idx[s] = (const int*)d_in[3 + 10 * l];
        A.sg.cnt[s] = wsw + degO[l];
        A.sg.rp [s] = wsw + rpO[l];
        A.sg.out[s] = wsw + eidO[l];
        A.sg.n  [s] = ESa[l];
        A.sg.nb [s] = NSa[l];
        A.sg.tstart[s] = tiles;
        tiles += (ESa[l] + 1023) / 1024;
    }
    A.sg.idx[3] = (const int*)d_in[5];              // cluster0
    A.sg.cnt[3] = wsw + cdeg0O;
    A.sg.rp [3] = wsw + crp0O;
    A.sg.out[3] = wsw + cnid0O;
    A.sg.n  [3] = NSa[0];
    A.sg.nb [3] = NSa[1];
    A.sg.tstart[3] = tiles;
    tiles += (NSa[0] + 1023) / 1024;
    A.sg.tstart[4] = tiles;                          // 148

    int hsB = 0;
    A.hb0[0] = 0;
    for (int j = 0; j < 4; j++) {
        A.hea[j] = (const float*)d_in[4 + 10 * (j + 1)];
        A.hE[j]  = ESa[j + 1];
        hsB += (ESa[j + 1] + 2047) / 2048;
        A.hb0[j + 1] = hsB;
    }
    A.hsB = hsB;                                     // 170

    hipMemsetAsync(d_ws, 0, zeroWords * 4, stream);

    k1_fuseA<<<1024 + TILES1 + hsB + tiles, 256, 0, stream>>>(A);   // 1598
    k2_fuseB<<<NBUK + NB1 + 1 + 4 + 5,      256, 0, stream>>>(A);   // 1546
    k3_fuseC<<<TILES1 + tiles,              256, 0, stream>>>(A);   // 404
    k4_fuseD<<<NB1 + 960,                   256, 0, stream>>>(A);   // 1472
    k5_conv1<<<NSa[1],                      256, 0, stream>>>(A);   // 16384
    coopP_k<23, 28><<<NSa[2],               256, 0, stream>>>(A, 2);
    coopP_k<31, 36><<<NSa[3],               256, 0, stream>>>(A, 3);
    coopP_k<39, 44><<<NSa[4],               256, 0, stream>>>(A, 4);
    k9_fc<<<1, 128, 0, stream>>>(A);
}

// Round 6
// 378.229 us; speedup vs baseline: 1.9834x; 1.0976x over previous
//
#include <hip/hip_runtime.h>
#include <hip/hip_fp16.h>
#include <math.h>

// ---------------------------------------------------------------------------
// Net_37512244363273: 5-level edge-conditioned graph conv + voxel pooling + FC
// Round 21: scatter-coalescing pass. R20 counters: k1 65us @930GB/s VALU 9%,
// k2 61us @299GB/s VALU 2.4% -- all dispatches bound by uncoalesced vmem
// transactions (~1 lane/cycle/CU; 64-way scatter = 64x a coalesced store).
//  - part0: 2048-edge tiles, 256 buckets (256 nodes). LDS hist -> 1 reserve
//    atomic/bucket -> local scan -> 32KB LDS staging sorted by bucket ->
//    coalesced runs of ~8 records to pay2. ~8x fewer write transactions.
//  - part1: same reservation-append for seg1 (rides in k1, computes L1
//    h-stats too). cnt1/colscan1/bktscan1/M1/M21 (column-strided scans that
//    dominated k2) are DELETED.
//  - bucket1: per-bucket LDS sort (load appended recs -> rank -> inv-rank ->
//    fully coalesced rec1 write), rides in k3.
//  - conv0c: 256 blocks stream ~64KB contiguous each, LDS nacc[7][256].
// Pipeline: memset | k1 part0+part1+hstats+hist | k2 conv0c+bs1scan+scanC+
// wstats | k3 scatter+bucket1 | k4 pool0 | k5 conv1 | k6-8 conv2-4 | k9 fc.
// ---------------------------------------------------------------------------

#define NT0   512                  // part0 tiles (2048 edges)
#define TSZ0  2048
#define NBK0  256                  // L0 buckets (dst>>8, 256 nodes each)
#define CAP0  4608                 // per-bucket capacity (avg 4096 + 8 sigma)
#define NT1   128                  // part1 tiles (2048 edges)
#define TSZ1  2048
#define NBK1  256                  // L1 buckets (dst>>6, 64 nodes each)
#define CAP1  1280                 // per-bucket capacity (avg 1024 + 8 sigma)

__device__ __forceinline__ float ftanh(float x) {
    float e = __expf(2.f * x);
    return 1.f - 2.f / (e + 1.f);
}

// order-preserving float<->uint (monotone): enables atomicMax-based fmax
__device__ __forceinline__ unsigned fenc(float f) {
    int b = __float_as_int(f);
    return (b < 0) ? ~(unsigned)b : ((unsigned)b | 0x80000000u);
}
__device__ __forceinline__ float fdec(unsigned u) {
    int b = (u & 0x80000000u) ? (int)(u & 0x7fffffffu) : ~(int)u;
    return __int_as_float(b);
}

// decode element i of a pooled raw row [CI-3 max-enc | 3 possum | 1 cnt]
__device__ __forceinline__ float row_val(const unsigned* __restrict__ row,
                                         int i, int CI) {
    float cn = __uint_as_float(row[CI]);
    if (i < CI - 3) return (cn == 0.f) ? 0.f : fdec(row[i]);
    return __uint_as_float(row[i]) / fmaxf(cn, 1.f);
}

struct Seg4 {                       // edge segs L2-4 + cluster0 seg
    const int* idx[4];
    int*       cnt[4];
    int*       rp [4];
    int*       out[4];
    int        n  [4];
    int        nb [4];
    int        tstart[5];
};

struct GA {
    // inputs
    const int *src0, *dst0; const float* ea0;
    const int *src1, *dst1; const float* ea1;
    const float *x0, *pos0;
    const int* cluster[5];
    const float *w1[5], *b1[5], *w2[5], *b2[5], *root[5], *bias[5];
    const int* srcE[3]; const float* eaE[3];
    const float *fc_w, *fc_b;
    // workspace
    int *bcnt, *bcnt1;              // [NBK0]/[NBK1] reservation counters
    float4 *pay2, *pay1, *rec1;
    float *y0, *xn0;
    unsigned* raw[5];               // pooled rows for levels 1-4
    float *H, *sq;
    int *bs1, *rp1;
    Seg4 sg;
    float* out;
    int hb0[4], hsB;                // hstats (levels 2-4 only)
};

// ---------------------------------------------------------------------------
// K1: part0 (512) | part1 (128) | hstats L2-4 (42) | hist 4 segs (148)
// Shared LDS (union across roles): 32KB staging + 2KB bucket-tags + 4KB scans
// ---------------------------------------------------------------------------
__global__ __launch_bounds__(256) void k1_fuseA(GA A)
{
    __shared__ float4 stg[TSZ0];                   // 32KB
    __shared__ unsigned char bkb[TSZ0];            // 2KB
    __shared__ int hb_[256], gb_[256], ls_[256], cu_[256];

    int B = blockIdx.x, t = threadIdx.x;

    if (B < NT0) {                                 // ---- part0-append ----
        hb_[t] = 0;
        __syncthreads();
        int base = B * TSZ0 + t;
        int dreg[8];
        #pragma unroll
        for (int k = 0; k < 8; k++) {
            dreg[k] = A.dst0[base + k * 256];
            atomicAdd(&hb_[dreg[k] >> 8], 1);
        }
        __syncthreads();
        int c = hb_[t];
        gb_[t] = c ? atomicAdd(&A.bcnt[t], c) : 0;
        ls_[t] = c;
        __syncthreads();
        for (int d = 1; d < 256; d <<= 1) {
            int u = (t >= d) ? ls_[t - d] : 0;
            __syncthreads();
            ls_[t] += u;
            __syncthreads();
        }
        int ex = ls_[t] - c;
        ls_[t] = ex;
        cu_[t] = ex;
        __syncthreads();

        float w1r[15], b1r[5];
        #pragma unroll
        for (int i = 0; i < 15; i++) w1r[i] = A.w1[0][i];
        #pragma unroll
        for (int i = 0; i < 5; i++)  b1r[i] = A.b1[0][i];
        float acc[20];
        #pragma unroll
        for (int i = 0; i < 20; i++) acc[i] = 0.f;
        #pragma unroll
        for (int k = 0; k < 8; k++) {
            int i = base + k * 256;
            int d = dreg[k];
            int sv = A.src0[i];
            float e0 = A.ea0[i * 3], e1 = A.ea0[i * 3 + 1], e2 = A.ea0[i * 3 + 2];
            float h[5];
            #pragma unroll
            for (int q = 0; q < 5; q++)
                h[q] = ftanh(e0 * w1r[q] + e1 * w1r[5 + q] + e2 * w1r[10 + q] + b1r[q]);
            int p = 5;
            #pragma unroll
            for (int q = 0; q < 5; q++) {
                acc[q] += h[q];
                #pragma unroll
                for (int q2 = q; q2 < 5; q2++) acc[p++] += h[q] * h[q2];
            }
            float xv = A.x0[sv];
            union HU { __half2 h2; float f; } p01, p23;
            p01.h2 = __floats2half2_rn(h[0], h[1]);
            p23.h2 = __floats2half2_rn(h[2], h[3]);
            unsigned wbits = ((unsigned)d << 16) |
                             (unsigned)__half_as_ushort(__float2half_rn(h[4]));
            int bk = d >> 8;
            int ps = atomicAdd(&cu_[bk], 1);
            stg[ps] = make_float4(xv, p01.f, p23.f, __uint_as_float(wbits));
            bkb[ps] = (unsigned char)bk;
        }
        __syncthreads();
        #pragma unroll
        for (int k = 0; k < 8; k++) {              // coalesced-run write-out
            int p = k * 256 + t;
            int bk = bkb[p];
            int off = gb_[bk] + (p - ls_[bk]);
            if (off < CAP0)
                A.pay2[(size_t)bk * CAP0 + off] = stg[p];
        }
        __syncthreads();
        float* red = (float*)cu_;
        int wid = t >> 6, lane = t & 63;
        #pragma unroll
        for (int v = 0; v < 20; v++) {
            float s = acc[v];
            #pragma unroll
            for (int o = 32; o; o >>= 1) s += __shfl_down(s, o);
            if (lane == 0) red[wid * 20 + v] = s;
        }
        __syncthreads();
        if (t < 20)
            atomicAdd(&A.H[t], red[t] + red[20 + t] + red[40 + t] + red[60 + t]);
        return;
    }
    B -= NT0;
    if (B < NT1) {                                 // ---- part1-append ----
        hb_[t] = 0;
        __syncthreads();
        int base = B * TSZ1 + t;
        int dreg[8];
        #pragma unroll
        for (int k = 0; k < 8; k++) {
            dreg[k] = A.dst1[base + k * 256];
            atomicAdd(&hb_[dreg[k] >> 6], 1);
        }
        __syncthreads();
        int c = hb_[t];
        gb_[t] = c ? atomicAdd(&A.bcnt1[t], c) : 0;
        ls_[t] = c;
        __syncthreads();
        for (int d = 1; d < 256; d <<= 1) {
            int u = (t >= d) ? ls_[t - d] : 0;
            __syncthreads();
            ls_[t] += u;
            __syncthreads();
        }
        int ex = ls_[t] - c;
        ls_[t] = ex;
        cu_[t] = ex;
        __syncthreads();

        float w1r[15], b1r[5];
        #pragma unroll
        for (int i = 0; i < 15; i++) w1r[i] = A.w1[1][i];
        #pragma unroll
        for (int i = 0; i < 5; i++)  b1r[i] = A.b1[1][i];
        float acc[20];
        #pragma unroll
        for (int i = 0; i < 20; i++) acc[i] = 0.f;
        #pragma unroll
        for (int k = 0; k < 8; k++) {
            int i = base + k * 256;
            int d = dreg[k];
            int sv = A.src1[i];
            float e0 = A.ea1[i * 3], e1 = A.ea1[i * 3 + 1], e2 = A.ea1[i * 3 + 2];
            float h[5];
            #pragma unroll
            for (int q = 0; q < 5; q++)
                h[q] = ftanh(e0 * w1r[q] + e1 * w1r[5 + q] + e2 * w1r[10 + q] + b1r[q]);
            int p = 5;
            #pragma unroll
            for (int q = 0; q < 5; q++) {
                acc[q] += h[q];
                #pragma unroll
                for (int q2 = q; q2 < 5; q2++) acc[p++] += h[q] * h[q2];
            }
            int bk = d >> 6;
            int ps = atomicAdd(&cu_[bk], 1);
            stg[ps] = make_float4(__int_as_float((d << 16) | sv), e0, e1, e2);
            bkb[ps] = (unsigned char)bk;
        }
        __syncthreads();
        #pragma unroll
        for (int k = 0; k < 8; k++) {
            int p = k * 256 + t;
            int bk = bkb[p];
            int off = gb_[bk] + (p - ls_[bk]);
            if (off < CAP1)
                A.pay1[(size_t)bk * CAP1 + off] = stg[p];
        }
        __syncthreads();
        float* red = (float*)cu_;
        int wid = t >> 6, lane = t & 63;
        #pragma unroll
        for (int v = 0; v < 20; v++) {
            float s = acc[v];
            #pragma unroll
            for (int o = 32; o; o >>= 1) s += __shfl_down(s, o);
            if (lane == 0) red[wid * 20 + v] = s;
        }
        __syncthreads();
        if (t < 20)
            atomicAdd(&A.H[20 + t], red[t] + red[20 + t] + red[40 + t] + red[60 + t]);
        return;
    }
    B -= NT1;
    if (B < A.hsB) {                               // ---- hstats (L2-4) ----
        const int K = 8;
        int j = 0;
        while (j < 2 && B >= A.hb0[j + 1]) j++;
        int bloc = B - A.hb0[j];
        const float* ea = A.eaE[j];
        const float* w1p = A.w1[j + 2];
        const float* b1p = A.b1[j + 2];
        static const int EJ[3] = {65536, 16384, 4096};
        int Ej = EJ[j];
        float w1r[15], b1r[5];
        #pragma unroll
        for (int i = 0; i < 15; i++) w1r[i] = w1p[i];
        #pragma unroll
        for (int i = 0; i < 5; i++)  b1r[i] = b1p[i];
        float acc[20];
        #pragma unroll
        for (int i = 0; i < 20; i++) acc[i] = 0.f;
        int base = bloc * 256 * K + t;
        for (int it = 0; it < K; it++) {
            int e = base + it * 256;
            if (e < Ej) {
                float e0 = ea[e * 3], e1 = ea[e * 3 + 1], e2 = ea[e * 3 + 2];
                float h[5];
                #pragma unroll
                for (int q = 0; q < 5; q++)
                    h[q] = ftanh(e0 * w1r[q] + e1 * w1r[5 + q] + e2 * w1r[10 + q] + b1r[q]);
                int p = 5;
                #pragma unroll
                for (int q = 0; q < 5; q++) {
                    acc[q] += h[q];
                    #pragma unroll
                    for (int q2 = q; q2 < 5; q2++) acc[p++] += h[q] * h[q2];
                }
            }
        }
        float* red = (float*)hb_;
        int wid = t >> 6, lane = t & 63;
        #pragma unroll
        for (int v = 0; v < 20; v++) {
            float s = acc[v];
            #pragma unroll
            for (int o = 32; o; o >>= 1) s += __shfl_down(s, o);
            if (lane == 0) red[wid * 20 + v] = s;
        }
        __syncthreads();
        if (t < 20)
            atomicAdd(&A.H[(j + 2) * 20 + t],
                      red[t] + red[20 + t] + red[40 + t] + red[60 + t]);
        return;
    }
    B -= A.hsB;
    {                                              // ---- hist (4 segs) ----
        int s = 0;
        while (s < 3 && B >= A.sg.tstart[s + 1]) s++;
        int i0 = (B - A.sg.tstart[s]) * 1024;
        const int* idx = A.sg.idx[s];
        int* cnt = A.sg.cnt[s];
        int n = A.sg.n[s];
        #pragma unroll
        for (int j = 0; j < 4; j++) {
            int i = i0 + j * 256 + t;
            if (i < n) atomicAdd(&cnt[idx[i]], 1);
        }
    }
}

// ---------------------------------------------------------------------------
// K2: conv0c (256) | bs1scan (1) | scanC (4) | wstats (5)
// ---------------------------------------------------------------------------
__global__ __launch_bounds__(256) void k2_fuseB(GA A)
{
    __shared__ float wsm[96];
    __shared__ float nacc[7 * NBK0];
    __shared__ int sc[256];
    int B = blockIdx.x, t = threadIdx.x;

    if (B < NBK0) {                                // ---- conv0c ----
        if (t < 60) wsm[t] = A.w2[0][t];
        else if (t >= 64  && t < 76)  wsm[60 + t - 64]  = A.b2[0][t - 64];
        else if (t >= 128 && t < 140) wsm[72 + t - 128] = A.root[0][t - 128];
        else if (t >= 192 && t < 204) wsm[84 + t - 192] = A.bias[0][t - 192];
        for (int u = t; u < 7 * NBK0; u += 256) nacc[u] = 0.f;
        __syncthreads();

        int n = A.bcnt[B];
        if (n > CAP0) n = CAP0;
        size_t base = (size_t)B * CAP0;
        for (int j = t; j < n; j += 256) {
            float4 R = A.pay2[base + j];
            union HU { float f; __half2 h2; } a01, a23;
            a01.f = R.y; a23.f = R.z;
            unsigned wbits = __float_as_uint(R.w);
            int rel = (int)(wbits >> 16) & 255;
            float xv = R.x;
            atomicAdd(&nacc[rel], xv);
            atomicAdd(&nacc[256 + rel],  __low2float(a01.h2)  * xv);
            atomicAdd(&nacc[512 + rel],  __high2float(a01.h2) * xv);
            atomicAdd(&nacc[768 + rel],  __low2float(a23.h2)  * xv);
            atomicAdd(&nacc[1024 + rel], __high2float(a23.h2) * xv);
            atomicAdd(&nacc[1280 + rel],
                      __half2float(__ushort_as_half((unsigned short)(wbits & 0xffffu))) * xv);
            atomicAdd(&nacc[1536 + rel], 1.f);
        }
        __syncthreads();

        int v0 = B << 8;
        for (int u = t; u < NBK0 * 12; u += 256) {
            int rel = u / 12, o = u - rel * 12;
            float dg = nacc[1536 + rel];
            float inv = 1.f / fmaxf(dg, 1.f);
            float msg = wsm[60 + o] * nacc[rel] + wsm[o] * nacc[256 + rel] +
                        wsm[12 + o] * nacc[512 + rel] + wsm[24 + o] * nacc[768 + rel] +
                        wsm[36 + o] * nacc[1024 + rel] + wsm[48 + o] * nacc[1280 + rel];
            float xv = A.x0[v0 + rel];
            A.y0[(size_t)(v0 + rel) * 12 + o] =
                msg * inv + xv * wsm[72 + o] + wsm[84 + o];
        }
        return;
    }
    B -= NBK0;
    if (B < 1) {                                   // ---- bs1scan ----
        int c = A.bcnt1[t];
        if (c > CAP1) c = CAP1;
        sc[t] = c;
        __syncthreads();
        for (int d = 1; d < 256; d <<= 1) {
            int u = (t >= d) ? sc[t - d] : 0;
            __syncthreads();
            sc[t] += u;
            __syncthreads();
        }
        A.bs1[t] = sc[t] - c;
        if (t == 255) { A.bs1[256] = sc[255]; A.rp1[16384] = sc[255]; }
        return;
    }
    B -= 1;
    if (B < 4) {                                   // ---- scanC (1 blk/seg) ----
        int s = B;
        int nb = A.sg.nb[s];
        const int* cnt = A.sg.cnt[s];
        int* rp = A.sg.rp[s];
        int VPT = nb >> 8;
        int i0 = t * VPT;
        int sum = 0;
        for (int k = 0; k < VPT; k++) sum += cnt[i0 + k];
        int acc = sum;
        sc[t] = acc;
        __syncthreads();
        for (int d = 1; d < 256; d <<= 1) {
            int t2 = (t >= d) ? sc[t - d] : 0;
            __syncthreads();
            acc += t2;
            sc[t] = acc;
            __syncthreads();
        }
        int running = acc - sum;
        for (int k = 0; k < VPT; k++) {
            rp[i0 + k] = running;
            running += cnt[i0 + k];
        }
        if (t == 255) rp[nb] = running;
        return;
    }
    B -= 4;
    {                                              // ---- wstats (wave 0) ----
        if (t >= 64) return;
        int l = B;
        const float* w2l = A.w2[l];
        const float* b2l = A.b2[l];
        static const int cicoA[5] = {12, 300, 644, 1116, 1716};
        int cico = cicoA[l];
        float d[21];
        #pragma unroll
        for (int i = 0; i < 21; i++) d[i] = 0.f;
        for (int u = t; u < cico; u += 64) {
            float b = b2l[u];
            float w[5];
            #pragma unroll
            for (int k = 0; k < 5; k++) w[k] = w2l[k * cico + u];
            int p = 0;
            #pragma unroll
            for (int k = 0; k < 5; k++) {
                #pragma unroll
                for (int k2 = k; k2 < 5; k2++) d[p++] += w[k] * w[k2];
            }
            #pragma unroll
            for (int k = 0; k < 5; k++) d[15 + k] += b * w[k];
            d[20] += b * b;
        }
        #pragma unroll
        for (int i = 0; i < 21; i++) {
            #pragma unroll
            for (int off = 32; off; off >>= 1) d[i] += __shfl_down(d[i], off);
        }
        if (t == 0) {
            static const int EA[5] = {1048576, 262144, 65536, 16384, 4096};
            const float* H1 = A.H + l * 20;
            const float* H2 = H1 + 5;
            float sq = (float)EA[l] * d[20];
            #pragma unroll
            for (int k = 0; k < 5; k++) sq += 2.f * d[15 + k] * H1[k];
            int p = 0;
            #pragma unroll
            for (int k = 0; k < 5; k++) {
                #pragma unroll
                for (int k2 = k; k2 < 5; k2++) {
                    sq += ((k == k2) ? 1.f : 2.f) * d[p] * H2[p];
                    p++;
                }
            }
            A.sq[l] = sq;
        }
    }
}

// ---------------------------------------------------------------------------
// K3: scatter 4 segs (148) | bucket1 LDS-sort (256)
// ---------------------------------------------------------------------------
__global__ __launch_bounds__(256) void k3_fuseC(GA A)
{
    __shared__ float4 st4[CAP1];                   // 20KB
    __shared__ short  inv[CAP1];                   // 2.5KB
    __shared__ int h64[64], l64[64], c64[64];
    int B = blockIdx.x, t = threadIdx.x;

    if (B < A.sg.tstart[4]) {                      // ---- scatter ----
        int s = 0;
        while (s < 3 && B >= A.sg.tstart[s + 1]) s++;
        int i0 = (B - A.sg.tstart[s]) * 1024;
        const int* idx = A.sg.idx[s];
        int* cnt = A.sg.cnt[s];
        const int* rp = A.sg.rp[s];
        int* out = A.sg.out[s];
        int n = A.sg.n[s];
        #pragma unroll
        for (int j = 0; j < 4; j++) {
            int i = i0 + j * 256 + t;
            if (i < n) {
                int d = idx[i];
                int p = atomicSub(&cnt[d], 1) - 1;
                out[rp[d] + p] = i;
            }
        }
        return;
    }
    B -= A.sg.tstart[4];
    {                                              // ---- bucket1 ----
        int b = B;
        int n = A.bcnt1[b];
        if (n > CAP1) n = CAP1;
        size_t base = (size_t)b * CAP1;
        for (int j = t; j < n; j += 256) st4[j] = A.pay1[base + j];
        if (t < 64) h64[t] = 0;
        __syncthreads();
        for (int j = t; j < n; j += 256) {
            int rel = (int)(__float_as_uint(st4[j].x) >> 16) & 63;
            atomicAdd(&h64[rel], 1);
        }
        __syncthreads();
        if (t < 64) {                              // wave-level exclusive scan
            int v = h64[t];
            int val = v;
            #pragma unroll
            for (int d = 1; d < 64; d <<= 1) {
                int u = __shfl_up(val, d);
                if (t >= d) val += u;
            }
            l64[t] = val - v;
            c64[t] = val - v;
        }
        __syncthreads();
        for (int j = t; j < n; j += 256) {
            int rel = (int)(__float_as_uint(st4[j].x) >> 16) & 63;
            int p = atomicAdd(&c64[rel], 1);
            inv[p] = (short)j;
        }
        __syncthreads();
        int lo = A.bs1[b];
        for (int j = t; j < n; j += 256)           // coalesced sorted write
            A.rec1[lo + j] = st4[inv[j]];
        if (t < 64) A.rp1[(b << 6) + t] = lo + l64[t];
    }
}

// ---------------------------------------------------------------------------
// K4: pool0 (960)
// ---------------------------------------------------------------------------
__global__ __launch_bounds__(256) void k4_pool0(GA A)
{
    int gt = blockIdx.x * 256 + threadIdx.x;
    if (gt >= 16384 * 15) return;
    int c = gt / 15, o = gt - c * 15;
    int r0 = A.sg.rp[3][c], r1 = A.sg.rp[3][c + 1];
    const int* cnid = A.sg.out[3];
    int d = r1 - r0;
    if (o < 12) {
        float m = -INFINITY;
        for (int j = r0; j < r1; j++)
            m = fmaxf(m, A.y0[(size_t)cnid[j] * 12 + o]);
        if (d == 0 || !isfinite(m)) m = 0.f;
        A.xn0[c * 15 + o] = m;
    } else {
        int k = o - 12;
        float sum = 0.f;
        for (int j = r0; j < r1; j++)
            sum += A.pos0[cnid[j] * 3 + k];
        A.xn0[c * 15 + o] = sum / fmaxf((float)d, 1.f);
    }
}

// ---------------------------------------------------------------------------
// K5: conv1 (block/node, streams rec1, plain xn0 input) + pool->raw1
// ---------------------------------------------------------------------------
__global__ __launch_bounds__(256) void k5_conv1(GA A)
{
    constexpr int CI = 15, CO = 20, CH = 48, CICO = CI * CO, RN = 24;
    __shared__ float w1s[20];
    __shared__ float4 recb[CH];
    __shared__ int   svb[CH];
    __shared__ float hb[CH * 6];
    __shared__ float xs[CH * CI];
    __shared__ float Sx[6 * CI];
    __shared__ float xown[CI];

    int t = threadIdx.x, v = blockIdx.x;
    if (t < 20) w1s[t] = (t < 15) ? A.w1[1][t] : A.b1[1][t - 15];
    if (t < CI) xown[t] = A.xn0[v * CI + t];
    int r0 = A.rp1[v], r1 = A.rp1[v + 1];
    int d = r1 - r0;
    float acc = 0.f;

    for (int c0 = r0; c0 < r1; c0 += CH) {
        int cn = min(CH, r1 - c0);
        if (t < cn) {
            float4 R = A.rec1[c0 + t];
            recb[t] = R;
            svb[t]  = (int)(__float_as_uint(R.x) & 0xffffu);
            hb[t * 6] = 1.f;
        }
        __syncthreads();
        if (t < cn * 5) {
            int j = t / 5, k = t % 5;
            float e0 = recb[j].y, e1 = recb[j].z, e2 = recb[j].w;
            hb[j * 6 + 1 + k] =
                ftanh(e0 * w1s[k] + e1 * w1s[5 + k] + e2 * w1s[10 + k] + w1s[15 + k]);
        }
        for (int u = t; u < cn * CI; u += 256) {
            int j = u / CI, i = u - j * CI;
            xs[u] = A.xn0[svb[j] * CI + i];
        }
        __syncthreads();
        if (t < 6 * CI) {
            int i = t / 6, k6 = t - (t / 6) * 6;
            for (int j = 0; j < cn; j++)
                acc += hb[j * 6 + k6] * xs[j * CI + i];
        }
        __syncthreads();
    }

    if (t < 6 * CI) Sx[t] = acc;
    __syncthreads();

    if (t < CO) {
        float m = 0.f;
        const float* w2 = A.w2[1];
        const float* b2 = A.b2[1];
        for (int i = 0; i < CI; i++) {
            m += b2[i * CO + t] * Sx[i * 6];
            #pragma unroll
            for (int k = 0; k < 5; k++)
                m += w2[k * CICO + i * CO + t] * Sx[i * 6 + 1 + k];
        }
        m /= fmaxf((float)d, 1.f);
        for (int i = 0; i < CI; i++) m += xown[i] * A.root[1][i * CO + t];
        m += A.bias[1][t];
        int c = A.cluster[1][v];
        unsigned* orow = A.raw[1] + (size_t)c * RN;
        atomicMax(&orow[t], fenc(m));
        if (t < 3) atomicAdd((float*)&orow[CO + t], xown[CI - 3 + t]);
        if (t == 0) atomicAdd((float*)&orow[CO + 3], 1.f);
    }
}

// ---------------------------------------------------------------------------
// K6-8: coop conv levels 2-4 + fused pool epilogue
// ---------------------------------------------------------------------------
template<int CI, int CO>
__global__ __launch_bounds__(256) void coopP_k(GA A, int l)
{
    constexpr int CH = 48, CICO = CI * CO, RL = CI + 1, RN = CO + 4;
    __shared__ float w1s[20];
    __shared__ int   eb[CH], svb[CH];
    __shared__ float hb[CH * 6];
    __shared__ float xs[CH * CI];
    __shared__ float Sx[6 * CI];
    __shared__ float xown[CI];

    int t = threadIdx.x, v = blockIdx.x;
    int s = l - 2;
    const unsigned* rin = A.raw[l - 1];
    const int* rp = A.sg.rp[s];
    const int* eid = A.sg.out[s];
    const int* src = A.srcE[s];
    const float* eattr = A.eaE[s];

    if (t < 20) w1s[t] = (t < 15) ? A.w1[l][t] : A.b1[l][t - 15];
    if (t < CI) xown[t] = row_val(rin + (size_t)v * RL, t, CI);
    int r0 = rp[v], r1 = rp[v + 1];
    int d = r1 - r0;
    float acc = 0.f;

    for (int c0 = r0; c0 < r1; c0 += CH) {
        int cn = min(CH, r1 - c0);
        if (t < cn) {
            int e = eid[c0 + t];
            eb[t]  = e;
            svb[t] = src[e];
            hb[t * 6] = 1.f;
        }
        __syncthreads();
        if (t < cn * 5) {
            int j = t / 5, k = t % 5;
            int e = eb[j];
            float e0 = eattr[e * 3], e1 = eattr[e * 3 + 1], e2 = eattr[e * 3 + 2];
            hb[j * 6 + 1 + k] =
                ftanh(e0 * w1s[k] + e1 * w1s[5 + k] + e2 * w1s[10 + k] + w1s[15 + k]);
        }
        for (int u = t; u < cn * CI; u += 256) {
            int j = u / CI, i = u - j * CI;
            xs[u] = row_val(rin + (size_t)svb[j] * RL, i, CI);
        }
        __syncthreads();
        if (t < 6 * CI) {
            int i = t / 6, k6 = t - (t / 6) * 6;
            for (int j = 0; j < cn; j++)
                acc += hb[j * 6 + k6] * xs[j * CI + i];
        }
        __syncthreads();
    }

    if (t < 6 * CI) Sx[t] = acc;
    __syncthreads();

    if (t < CO) {
        float m = 0.f;
        const float* w2 = A.w2[l];
        const float* b2 = A.b2[l];
        for (int i = 0; i < CI; i++) {
            m += b2[i * CO + t] * Sx[i * 6];
            #pragma unroll
            for (int k = 0; k < 5; k++)
                m += w2[k * CICO + i * CO + t] * Sx[i * 6 + 1 + k];
        }
        m /= fmaxf((float)d, 1.f);
        for (int i = 0; i < CI; i++) m += xown[i] * A.root[l][i * CO + t];
        m += A.bias[l][t];
        int c = A.cluster[l][v];
        unsigned* orow = A.raw[l] + (size_t)c * RN;
        atomicMax(&orow[t], fenc(m));
        if (t < 3) atomicAdd((float*)&orow[CO + t], xown[CI - 3 + t]);
        if (t == 0) atomicAdd((float*)&orow[CO + 3], 1.f);
    }
}

// ---------------------------------------------------------------------------
// K9: fc (decodes raw[4])
// ---------------------------------------------------------------------------
__global__ __launch_bounds__(128) void k9_fc(GA A)
{
    __shared__ float feat[8 * 376];
    __shared__ float logit[80];
    __shared__ float roff[8];
    const unsigned* r5 = A.raw[4];
    for (int idx = threadIdx.x; idx < 64 * 47; idx += 128) {
        int n = idx / 47, i = idx - n * 47;
        int b = n >> 3, s = n & 7;
        feat[b * 376 + s * 47 + i] = row_val(r5 + (size_t)n * 48, i, 47);
    }
    __syncthreads();
    int t = threadIdx.x;
    if (t < 80) {
        int b = t / 10, j = t % 10;
        float acc = A.fc_b[j];
        for (int k = 0; k < 376; k++) acc += feat[b * 376 + k] * A.fc_w[k * 10 + j];
        logit[t] = acc;
    }
    __syncthreads();
    if (t < 8) {
        float m = -1e30f;
        for (int j = 0; j < 10; j++) m = fmaxf(m, logit[t * 10 + j]);
        float ssum = 0.f;
        for (int j = 0; j < 10; j++) ssum += expf(logit[t * 10 + j] - m);
        roff[t] = m + logf(ssum);
    }
    __syncthreads();
    if (t < 80) A.out[t] = logit[t] - roff[t / 10];
    if (t == 0) {
        const float* sq = A.sq;
        float closs = 0.f;
        closs += sq[0] * (1.0f / 12582912.0f);
        closs += sq[1] * (1.0f / 78643200.0f);
        closs += sq[2] * (1.0f / 42205184.0f);
        closs += sq[3] * (1.0f / 18284544.0f);
        closs += sq[4] * (1.0f / 7028736.0f);
        A.out[80] = closs;
    }
}

// ---------------------------------------------------------------------------

extern "C" void kernel_launch(void* const* d_in, const int* in_sizes, int n_in,
                              void* d_out, int out_size, void* d_ws, size_t ws_size,
                              hipStream_t stream)
{
    static const int NSa[6] = {65536, 16384, 4096, 1024, 256, 64};
    static const int ESa[5] = {1048576, 262144, 65536, 16384, 4096};
    static const int RNa[5] = {16, 24, 32, 40, 48};   // raw row widths (words)

    // ---- workspace layout (words) ----
    int* wsw = (int*)d_ws;
    size_t off = 0;
    auto alw = [&](size_t n) -> size_t {
        size_t p = off; off += (n + 63) & ~(size_t)63; return p;
    };
    // zeroed region
    size_t degO[5];
    for (int l = 2; l < 5; l++) degO[l] = alw(NSa[l]);
    size_t cdeg0O = alw(NSa[1]);                      // cluster0 counts
    size_t HO    = alw(100);
    size_t bcO   = alw(NBK0);
    size_t bc1O  = alw(NBK1);
    size_t rawO[5];
    for (int l = 1; l < 5; l++) rawO[l] = alw((size_t)NSa[l + 1] * RNa[l]);
    size_t zeroWords = off;
    // non-zeroed
    size_t rpO[5], eidO[5];
    for (int l = 2; l < 5; l++) rpO[l]  = alw(NSa[l] + 1);
    size_t crp0O = alw(NSa[1] + 1);
    for (int l = 2; l < 5; l++) eidO[l] = alw(ESa[l]);
    size_t cnid0O = alw(NSa[0]);
    size_t pay2O = alw((size_t)NBK0 * CAP0 * 4);
    size_t y0O   = alw((size_t)NSa[0] * 12);
    size_t xn0O  = alw((size_t)NSa[1] * 15);
    size_t bs1O  = alw(NBK1 + 1);
    size_t pay1O = alw((size_t)NBK1 * CAP1 * 4);
    size_t rec1O = alw((size_t)ESa[1] * 4);
    size_t rp1O  = alw(NSa[1] + 1);
    size_t sqO   = alw(8);

    GA A{};
    A.src0 = (const int*)d_in[2];  A.dst0 = (const int*)d_in[3];
    A.ea0  = (const float*)d_in[4];
    A.src1 = (const int*)d_in[12]; A.dst1 = (const int*)d_in[13];
    A.ea1  = (const float*)d_in[14];
    A.x0   = (const float*)d_in[0];
    A.pos0 = (const float*)d_in[1];
    for (int l = 0; l < 5; l++) {
        A.cluster[l] = (const int*)d_in[5 + 10 * l];
        A.w1[l]   = (const float*)d_in[6 + 10 * l];
        A.b1[l]   = (const float*)d_in[7 + 10 * l];
        A.w2[l]   = (const float*)d_in[8 + 10 * l];
        A.b2[l]   = (const float*)d_in[9 + 10 * l];
        A.root[l] = (const float*)d_in[10 + 10 * l];
        A.bias[l] = (const float*)d_in[11 + 10 * l];
    }
    for (int s = 0; s < 3; s++) {
        A.srcE[s] = (const int*)d_in[2 + 10 * (s + 2)];
        A.eaE[s]  = (const float*)d_in[4 + 10 * (s + 2)];
    }
    A.fc_w = (const float*)d_in[52];
    A.fc_b = (const float*)d_in[53];
    A.bcnt  = wsw + bcO;
    A.bcnt1 = wsw + bc1O;
    A.pay2 = (float4*)(wsw + pay2O);
    A.pay1 = (float4*)(wsw + pay1O);
    A.rec1 = (float4*)(wsw + rec1O);
    A.y0   = (float*)(wsw + y0O);
    A.xn0  = (float*)(wsw + xn0O);
    for (int l = 1; l < 5; l++) A.raw[l] = (unsigned*)(wsw + rawO[l]);
    A.H  = (float*)(wsw + HO);
    A.sq = (float*)(wsw + sqO);
    A.bs1 = wsw + bs1O;
    A.rp1 = wsw + rp1O;
    A.out = (float*)d_out;

    // seg descriptors: 0-2 = edge segs L2-4, 3 = cluster0
    int tiles = 0;
    for (int s = 0; s < 3; s++) {
        int l = s + 2;
        A.sg.idx[s] = (const int*)d_in[3 + 10 * l];
        A.sg.cnt[s] = wsw + degO[l];
        A.sg.rp [s] = wsw + rpO[l];
        A.sg.out[s] = wsw + eidO[l];
        A.sg.n  [s] = ESa[l];
        A.sg.nb [s] = NSa[l];
        A.sg.tstart[s] = tiles;
        tiles += (ESa[l] + 1023) / 1024;
    }
    A.sg.idx[3] = (const int*)d_in[5];              // cluster0
    A.sg.cnt[3] = wsw + cdeg0O;
    A.sg.rp [3] = wsw + crp0O;
    A.sg.out[3] = wsw + cnid0O;
    A.sg.n  [3] = NSa[0];
    A.sg.nb [3] = NSa[1];
    A.sg.tstart[3] = tiles;
    tiles += (NSa[0] + 1023) / 1024;
    A.sg.tstart[4] = tiles;                          // 148

    int hsB = 0;
    A.hb0[0] = 0;
    for (int j = 0; j < 3; j++) {                    // hstats: levels 2-4
        hsB += (ESa[j + 2] + 2047) / 2048;
        A.hb0[j + 1] = hsB;
    }
    A.hsB = hsB;                                     // 42

    hipMemsetAsync(d_ws, 0, zeroWords * 4, stream);

    k1_fuseA<<<NT0 + NT1 + hsB + tiles, 256, 0, stream>>>(A);   // 830
    k2_fuseB<<<NBK0 + 1 + 4 + 5,        256, 0, stream>>>(A);   // 266
    k3_fuseC<<<tiles + NBK1,            256, 0, stream>>>(A);   // 404
    k4_pool0<<<(16384 * 15 + 255) / 256, 256, 0, stream>>>(A);  // 960
    k5_conv1<<<NSa[1],                  256, 0, stream>>>(A);   // 16384
    coopP_k<23, 28><<<NSa[2],           256, 0, stream>>>(A, 2);
    coopP_k<31, 36><<<NSa[3],           256, 0, stream>>>(A, 3);
    coopP_k<39, 44><<<NSa[4],           256, 0, stream>>>(A, 4);
    k9_fc<<<1, 128, 0, stream>>>(A);
}

// Round 7
// 338.929 us; speedup vs baseline: 2.2134x; 1.1160x over previous
//
#include <hip/hip_runtime.h>
#include <hip/hip_fp16.h>
#include <math.h>

// ---------------------------------------------------------------------------
// Net_37512244363273: 5-level edge-conditioned graph conv + voxel pooling + FC
// Round 22: LDS-atomic-count pass. Evidence: k2 = 60-61us in BOTH R20 (1024
// conv0c blocks) and R21 (256 blocks) -- invariant under repartition => bound
// by TOTAL LDS atomics (7.3M x ~4.4cyc / 256 CU = 52us), not occupancy.
//  - conv0c v2: chunked counting-sort. Per 1024-record chunk: stage in LDS,
//    hist by node key (1 atomic/rec), scan, rank (1 atomic/rec), thread t
//    serially sums node t's contiguous run into REGISTERS. 7.3M -> 2.1M.
//  - scanC cluster0 (16384, was stride-64 uncoalesced on 1 block): dedicated
//    coalesced role, 2 passes of 32KB LDS staging.
// Everything else identical to R21 (passed, absmax 0.0078).
// Pipeline: memset | k1 part0+part1+hstats+hist | k2 conv0c+bs1scan+scanC+
// scanC3+wstats | k3 scatter+bucket1 | k4 pool0 | k5 conv1 | k6-8 conv2-4 |
// k9 fc.
// ---------------------------------------------------------------------------

#define NT0   512                  // part0 tiles (2048 edges)
#define TSZ0  2048
#define NBK0  256                  // L0 buckets (dst>>8, 256 nodes each)
#define CAP0  4608                 // per-bucket capacity (avg 4096 + 8 sigma)
#define NT1   128                  // part1 tiles (2048 edges)
#define TSZ1  2048
#define NBK1  256                  // L1 buckets (dst>>6, 64 nodes each)
#define CAP1  1280                 // per-bucket capacity (avg 1024 + 8 sigma)

__device__ __forceinline__ float ftanh(float x) {
    float e = __expf(2.f * x);
    return 1.f - 2.f / (e + 1.f);
}

// order-preserving float<->uint (monotone): enables atomicMax-based fmax
__device__ __forceinline__ unsigned fenc(float f) {
    int b = __float_as_int(f);
    return (b < 0) ? ~(unsigned)b : ((unsigned)b | 0x80000000u);
}
__device__ __forceinline__ float fdec(unsigned u) {
    int b = (u & 0x80000000u) ? (int)(u & 0x7fffffffu) : ~(int)u;
    return __int_as_float(b);
}

// decode element i of a pooled raw row [CI-3 max-enc | 3 possum | 1 cnt]
__device__ __forceinline__ float row_val(const unsigned* __restrict__ row,
                                         int i, int CI) {
    float cn = __uint_as_float(row[CI]);
    if (i < CI - 3) return (cn == 0.f) ? 0.f : fdec(row[i]);
    return __uint_as_float(row[i]) / fmaxf(cn, 1.f);
}

struct Seg4 {                       // edge segs L2-4 + cluster0 seg
    const int* idx[4];
    int*       cnt[4];
    int*       rp [4];
    int*       out[4];
    int        n  [4];
    int        nb [4];
    int        tstart[5];
};

struct GA {
    // inputs
    const int *src0, *dst0; const float* ea0;
    const int *src1, *dst1; const float* ea1;
    const float *x0, *pos0;
    const int* cluster[5];
    const float *w1[5], *b1[5], *w2[5], *b2[5], *root[5], *bias[5];
    const int* srcE[3]; const float* eaE[3];
    const float *fc_w, *fc_b;
    // workspace
    int *bcnt, *bcnt1;              // [NBK0]/[NBK1] reservation counters
    float4 *pay2, *pay1, *rec1;
    float *y0, *xn0;
    unsigned* raw[5];               // pooled rows for levels 1-4
    float *H, *sq;
    int *bs1, *rp1;
    Seg4 sg;
    float* out;
    int hb0[4], hsB;                // hstats (levels 2-4 only)
};

// ---------------------------------------------------------------------------
// K1: part0 (512) | part1 (128) | hstats L2-4 (42) | hist 4 segs (148)
// Shared LDS (union across roles): 32KB staging + 2KB bucket-tags + 4KB scans
// ---------------------------------------------------------------------------
__global__ __launch_bounds__(256) void k1_fuseA(GA A)
{
    __shared__ float4 stg[TSZ0];                   // 32KB
    __shared__ unsigned char bkb[TSZ0];            // 2KB
    __shared__ int hb_[256], gb_[256], ls_[256], cu_[256];

    int B = blockIdx.x, t = threadIdx.x;

    if (B < NT0) {                                 // ---- part0-append ----
        hb_[t] = 0;
        __syncthreads();
        int base = B * TSZ0 + t;
        int dreg[8];
        #pragma unroll
        for (int k = 0; k < 8; k++) {
            dreg[k] = A.dst0[base + k * 256];
            atomicAdd(&hb_[dreg[k] >> 8], 1);
        }
        __syncthreads();
        int c = hb_[t];
        gb_[t] = c ? atomicAdd(&A.bcnt[t], c) : 0;
        ls_[t] = c;
        __syncthreads();
        for (int d = 1; d < 256; d <<= 1) {
            int u = (t >= d) ? ls_[t - d] : 0;
            __syncthreads();
            ls_[t] += u;
            __syncthreads();
        }
        int ex = ls_[t] - c;
        ls_[t] = ex;
        cu_[t] = ex;
        __syncthreads();

        float w1r[15], b1r[5];
        #pragma unroll
        for (int i = 0; i < 15; i++) w1r[i] = A.w1[0][i];
        #pragma unroll
        for (int i = 0; i < 5; i++)  b1r[i] = A.b1[0][i];
        float acc[20];
        #pragma unroll
        for (int i = 0; i < 20; i++) acc[i] = 0.f;
        #pragma unroll
        for (int k = 0; k < 8; k++) {
            int i = base + k * 256;
            int d = dreg[k];
            int sv = A.src0[i];
            float e0 = A.ea0[i * 3], e1 = A.ea0[i * 3 + 1], e2 = A.ea0[i * 3 + 2];
            float h[5];
            #pragma unroll
            for (int q = 0; q < 5; q++)
                h[q] = ftanh(e0 * w1r[q] + e1 * w1r[5 + q] + e2 * w1r[10 + q] + b1r[q]);
            int p = 5;
            #pragma unroll
            for (int q = 0; q < 5; q++) {
                acc[q] += h[q];
                #pragma unroll
                for (int q2 = q; q2 < 5; q2++) acc[p++] += h[q] * h[q2];
            }
            float xv = A.x0[sv];
            union HU { __half2 h2; float f; } p01, p23;
            p01.h2 = __floats2half2_rn(h[0], h[1]);
            p23.h2 = __floats2half2_rn(h[2], h[3]);
            unsigned wbits = ((unsigned)d << 16) |
                             (unsigned)__half_as_ushort(__float2half_rn(h[4]));
            int bk = d >> 8;
            int ps = atomicAdd(&cu_[bk], 1);
            stg[ps] = make_float4(xv, p01.f, p23.f, __uint_as_float(wbits));
            bkb[ps] = (unsigned char)bk;
        }
        __syncthreads();
        #pragma unroll
        for (int k = 0; k < 8; k++) {              // coalesced-run write-out
            int p = k * 256 + t;
            int bk = bkb[p];
            int off = gb_[bk] + (p - ls_[bk]);
            if (off < CAP0)
                A.pay2[(size_t)bk * CAP0 + off] = stg[p];
        }
        __syncthreads();
        float* red = (float*)cu_;
        int wid = t >> 6, lane = t & 63;
        #pragma unroll
        for (int v = 0; v < 20; v++) {
            float s = acc[v];
            #pragma unroll
            for (int o = 32; o; o >>= 1) s += __shfl_down(s, o);
            if (lane == 0) red[wid * 20 + v] = s;
        }
        __syncthreads();
        if (t < 20)
            atomicAdd(&A.H[t], red[t] + red[20 + t] + red[40 + t] + red[60 + t]);
        return;
    }
    B -= NT0;
    if (B < NT1) {                                 // ---- part1-append ----
        hb_[t] = 0;
        __syncthreads();
        int base = B * TSZ1 + t;
        int dreg[8];
        #pragma unroll
        for (int k = 0; k < 8; k++) {
            dreg[k] = A.dst1[base + k * 256];
            atomicAdd(&hb_[dreg[k] >> 6], 1);
        }
        __syncthreads();
        int c = hb_[t];
        gb_[t] = c ? atomicAdd(&A.bcnt1[t], c) : 0;
        ls_[t] = c;
        __syncthreads();
        for (int d = 1; d < 256; d <<= 1) {
            int u = (t >= d) ? ls_[t - d] : 0;
            __syncthreads();
            ls_[t] += u;
            __syncthreads();
        }
        int ex = ls_[t] - c;
        ls_[t] = ex;
        cu_[t] = ex;
        __syncthreads();

        float w1r[15], b1r[5];
        #pragma unroll
        for (int i = 0; i < 15; i++) w1r[i] = A.w1[1][i];
        #pragma unroll
        for (int i = 0; i < 5; i++)  b1r[i] = A.b1[1][i];
        float acc[20];
        #pragma unroll
        for (int i = 0; i < 20; i++) acc[i] = 0.f;
        #pragma unroll
        for (int k = 0; k < 8; k++) {
            int i = base + k * 256;
            int d = dreg[k];
            int sv = A.src1[i];
            float e0 = A.ea1[i * 3], e1 = A.ea1[i * 3 + 1], e2 = A.ea1[i * 3 + 2];
            float h[5];
            #pragma unroll
            for (int q = 0; q < 5; q++)
                h[q] = ftanh(e0 * w1r[q] + e1 * w1r[5 + q] + e2 * w1r[10 + q] + b1r[q]);
            int p = 5;
            #pragma unroll
            for (int q = 0; q < 5; q++) {
                acc[q] += h[q];
                #pragma unroll
                for (int q2 = q; q2 < 5; q2++) acc[p++] += h[q] * h[q2];
            }
            int bk = d >> 6;
            int ps = atomicAdd(&cu_[bk], 1);
            stg[ps] = make_float4(__int_as_float((d << 16) | sv), e0, e1, e2);
            bkb[ps] = (unsigned char)bk;
        }
        __syncthreads();
        #pragma unroll
        for (int k = 0; k < 8; k++) {
            int p = k * 256 + t;
            int bk = bkb[p];
            int off = gb_[bk] + (p - ls_[bk]);
            if (off < CAP1)
                A.pay1[(size_t)bk * CAP1 + off] = stg[p];
        }
        __syncthreads();
        float* red = (float*)cu_;
        int wid = t >> 6, lane = t & 63;
        #pragma unroll
        for (int v = 0; v < 20; v++) {
            float s = acc[v];
            #pragma unroll
            for (int o = 32; o; o >>= 1) s += __shfl_down(s, o);
            if (lane == 0) red[wid * 20 + v] = s;
        }
        __syncthreads();
        if (t < 20)
            atomicAdd(&A.H[20 + t], red[t] + red[20 + t] + red[40 + t] + red[60 + t]);
        return;
    }
    B -= NT1;
    if (B < A.hsB) {                               // ---- hstats (L2-4) ----
        const int K = 8;
        int j = 0;
        while (j < 2 && B >= A.hb0[j + 1]) j++;
        int bloc = B - A.hb0[j];
        const float* ea = A.eaE[j];
        const float* w1p = A.w1[j + 2];
        const float* b1p = A.b1[j + 2];
        static const int EJ[3] = {65536, 16384, 4096};
        int Ej = EJ[j];
        float w1r[15], b1r[5];
        #pragma unroll
        for (int i = 0; i < 15; i++) w1r[i] = w1p[i];
        #pragma unroll
        for (int i = 0; i < 5; i++)  b1r[i] = b1p[i];
        float acc[20];
        #pragma unroll
        for (int i = 0; i < 20; i++) acc[i] = 0.f;
        int base = bloc * 256 * K + t;
        for (int it = 0; it < K; it++) {
            int e = base + it * 256;
            if (e < Ej) {
                float e0 = ea[e * 3], e1 = ea[e * 3 + 1], e2 = ea[e * 3 + 2];
                float h[5];
                #pragma unroll
                for (int q = 0; q < 5; q++)
                    h[q] = ftanh(e0 * w1r[q] + e1 * w1r[5 + q] + e2 * w1r[10 + q] + b1r[q]);
                int p = 5;
                #pragma unroll
                for (int q = 0; q < 5; q++) {
                    acc[q] += h[q];
                    #pragma unroll
                    for (int q2 = q; q2 < 5; q2++) acc[p++] += h[q] * h[q2];
                }
            }
        }
        float* red = (float*)hb_;
        int wid = t >> 6, lane = t & 63;
        #pragma unroll
        for (int v = 0; v < 20; v++) {
            float s = acc[v];
            #pragma unroll
            for (int o = 32; o; o >>= 1) s += __shfl_down(s, o);
            if (lane == 0) red[wid * 20 + v] = s;
        }
        __syncthreads();
        if (t < 20)
            atomicAdd(&A.H[(j + 2) * 20 + t],
                      red[t] + red[20 + t] + red[40 + t] + red[60 + t]);
        return;
    }
    B -= A.hsB;
    {                                              // ---- hist (4 segs) ----
        int s = 0;
        while (s < 3 && B >= A.sg.tstart[s + 1]) s++;
        int i0 = (B - A.sg.tstart[s]) * 1024;
        const int* idx = A.sg.idx[s];
        int* cnt = A.sg.cnt[s];
        int n = A.sg.n[s];
        #pragma unroll
        for (int j = 0; j < 4; j++) {
            int i = i0 + j * 256 + t;
            if (i < n) atomicAdd(&cnt[idx[i]], 1);
        }
    }
}

// ---------------------------------------------------------------------------
// K2: conv0c v2 (256) | bs1scan (1) | scanC segs 0-2 (3) | scanC3 (1) |
//     wstats (5).  LDS pool 34KB (union across roles).
// ---------------------------------------------------------------------------
__global__ __launch_bounds__(256) void k2_fuseB(GA A)
{
    __shared__ alignas(16) char poolc[34048];
    int B = blockIdx.x, t = threadIdx.x;

    if (B < NBK0) {                                // ---- conv0c v2 ----
        float4* stg = (float4*)poolc;                          // 16KB
        float*  Sx  = (float*)(poolc + 16384);                 // 7KB
        unsigned char* key = (unsigned char*)(poolc + 23552);  // 1KB
        short* inv = (short*)(poolc + 24576);                  // 2KB
        int* hist = (int*)(poolc + 26624);
        int* st   = (int*)(poolc + 27648);
        int* cur  = (int*)(poolc + 28672);
        float* wsm = (float*)(poolc + 29696);                  // 96 floats

        if (t < 60) wsm[t] = A.w2[0][t];
        else if (t >= 64  && t < 76)  wsm[60 + t - 64]  = A.b2[0][t - 64];
        else if (t >= 128 && t < 140) wsm[72 + t - 128] = A.root[0][t - 128];
        else if (t >= 192 && t < 204) wsm[84 + t - 192] = A.bias[0][t - 192];

        int n = A.bcnt[B];
        if (n > CAP0) n = CAP0;
        size_t base = (size_t)B * CAP0;
        float s0 = 0.f, s1 = 0.f, s2 = 0.f, s3 = 0.f, s4 = 0.f, s5 = 0.f, dg = 0.f;

        for (int c0 = 0; c0 < n; c0 += 1024) {
            int cn = min(1024, n - c0);
            hist[t] = 0;
            __syncthreads();
            #pragma unroll
            for (int k = 0; k < 4; k++) {          // load + hist (1 atomic/rec)
                int j = k * 256 + t;
                if (j < cn) {
                    float4 R = A.pay2[base + c0 + j];
                    stg[j] = R;
                    int rel = (int)(__float_as_uint(R.w) >> 16) & 255;
                    key[j] = (unsigned char)rel;
                    atomicAdd(&hist[rel], 1);
                }
            }
            __syncthreads();
            int h = hist[t];                       // block scan
            int acc = h;
            st[t] = acc;
            __syncthreads();
            for (int d = 1; d < 256; d <<= 1) {
                int u = (t >= d) ? st[t - d] : 0;
                __syncthreads();
                acc += u;
                st[t] = acc;
                __syncthreads();
            }
            int ex = acc - h;
            st[t] = ex;
            cur[t] = ex;
            __syncthreads();
            #pragma unroll
            for (int k = 0; k < 4; k++) {          // rank (1 atomic/rec)
                int j = k * 256 + t;
                if (j < cn) {
                    int p = atomicAdd(&cur[key[j]], 1);
                    inv[p] = (short)j;
                }
            }
            __syncthreads();
            for (int q = st[t]; q < cur[t]; q++) { // serial run sum, no atomics
                float4 R = stg[inv[q]];
                union HU { float f; __half2 h2; } a01, a23;
                a01.f = R.y; a23.f = R.z;
                unsigned wbits = __float_as_uint(R.w);
                float xv = R.x;
                s0 += xv;
                s1 += __low2float(a01.h2)  * xv;
                s2 += __high2float(a01.h2) * xv;
                s3 += __low2float(a23.h2)  * xv;
                s4 += __high2float(a23.h2) * xv;
                s5 += __half2float(__ushort_as_half((unsigned short)(wbits & 0xffffu))) * xv;
                dg += 1.f;
            }
            __syncthreads();
        }
        Sx[t] = s0;        Sx[256 + t] = s1;  Sx[512 + t] = s2;
        Sx[768 + t] = s3;  Sx[1024 + t] = s4; Sx[1280 + t] = s5;
        Sx[1536 + t] = dg;
        __syncthreads();
        int v0 = B << 8;
        for (int u = t; u < 256 * 12; u += 256) {
            int rel = u / 12, o = u - rel * 12;
            float dgv = Sx[1536 + rel];
            float invd = 1.f / fmaxf(dgv, 1.f);
            float msg = wsm[60 + o] * Sx[rel] + wsm[o] * Sx[256 + rel] +
                        wsm[12 + o] * Sx[512 + rel] + wsm[24 + o] * Sx[768 + rel] +
                        wsm[36 + o] * Sx[1024 + rel] + wsm[48 + o] * Sx[1280 + rel];
            float xv = A.x0[v0 + rel];
            A.y0[(size_t)(v0 + rel) * 12 + o] =
                msg * invd + xv * wsm[72 + o] + wsm[84 + o];
        }
        return;
    }
    B -= NBK0;
    int* sc = (int*)poolc;
    if (B < 1) {                                   // ---- bs1scan ----
        int c = A.bcnt1[t];
        if (c > CAP1) c = CAP1;
        sc[t] = c;
        __syncthreads();
        for (int d = 1; d < 256; d <<= 1) {
            int u = (t >= d) ? sc[t - d] : 0;
            __syncthreads();
            sc[t] += u;
            __syncthreads();
        }
        A.bs1[t] = sc[t] - c;
        if (t == 255) { A.bs1[256] = sc[255]; A.rp1[16384] = sc[255]; }
        return;
    }
    B -= 1;
    if (B < 3) {                                   // ---- scanC segs 0-2 ----
        int s = B;
        int nb = A.sg.nb[s];
        const int* cnt = A.sg.cnt[s];
        int* rp = A.sg.rp[s];
        int VPT = nb >> 8;
        int i0 = t * VPT;
        int sum = 0;
        for (int k = 0; k < VPT; k++) sum += cnt[i0 + k];
        int acc = sum;
        sc[t] = acc;
        __syncthreads();
        for (int d = 1; d < 256; d <<= 1) {
            int t2 = (t >= d) ? sc[t - d] : 0;
            __syncthreads();
            acc += t2;
            sc[t] = acc;
            __syncthreads();
        }
        int running = acc - sum;
        for (int k = 0; k < VPT; k++) {
            rp[i0 + k] = running;
            running += cnt[i0 + k];
        }
        if (t == 255) rp[nb] = running;
        return;
    }
    B -= 3;
    if (B < 1) {                                   // ---- scanC3 (cluster0) ----
        int* big = (int*)poolc;                    // 32KB
        int* scx = (int*)(poolc + 32768);          // 1KB
        int* tot = (int*)(poolc + 33792);
        const int* cnt = A.sg.cnt[3];
        int* rp = A.sg.rp[3];
        int carry = 0;
        for (int p = 0; p < 2; p++) {
            if (p == 1) carry = tot[0];
            #pragma unroll
            for (int k = 0; k < 32; k++)           // coalesced load
                big[k * 256 + t] = cnt[p * 8192 + k * 256 + t];
            __syncthreads();
            int b0 = t * 32;
            int s = 0;
            #pragma unroll
            for (int j = 0; j < 32; j++) s += big[b0 + j];
            int acc = s;
            scx[t] = acc;
            __syncthreads();
            for (int d = 1; d < 256; d <<= 1) {
                int u = (t >= d) ? scx[t - d] : 0;
                __syncthreads();
                acc += u;
                scx[t] = acc;
                __syncthreads();
            }
            if (t == 255) tot[0] = carry + acc;
            int run = carry + acc - s;
            #pragma unroll
            for (int j = 0; j < 32; j++) {
                int v = big[b0 + j];
                big[b0 + j] = run;
                run += v;
            }
            __syncthreads();
            #pragma unroll
            for (int k = 0; k < 32; k++)           // coalesced store
                rp[p * 8192 + k * 256 + t] = big[k * 256 + t];
            __syncthreads();
        }
        if (t == 255) rp[16384] = tot[0];
        return;
    }
    B -= 1;
    {                                              // ---- wstats (wave 0) ----
        if (t >= 64) return;
        int l = B;
        const float* w2l = A.w2[l];
        const float* b2l = A.b2[l];
        static const int cicoA[5] = {12, 300, 644, 1116, 1716};
        int cico = cicoA[l];
        float d[21];
        #pragma unroll
        for (int i = 0; i < 21; i++) d[i] = 0.f;
        for (int u = t; u < cico; u += 64) {
            float b = b2l[u];
            float w[5];
            #pragma unroll
            for (int k = 0; k < 5; k++) w[k] = w2l[k * cico + u];
            int p = 0;
            #pragma unroll
            for (int k = 0; k < 5; k++) {
                #pragma unroll
                for (int k2 = k; k2 < 5; k2++) d[p++] += w[k] * w[k2];
            }
            #pragma unroll
            for (int k = 0; k < 5; k++) d[15 + k] += b * w[k];
            d[20] += b * b;
        }
        #pragma unroll
        for (int i = 0; i < 21; i++) {
            #pragma unroll
            for (int off = 32; off; off >>= 1) d[i] += __shfl_down(d[i], off);
        }
        if (t == 0) {
            static const int EA[5] = {1048576, 262144, 65536, 16384, 4096};
            const float* H1 = A.H + l * 20;
            const float* H2 = H1 + 5;
            float sq = (float)EA[l] * d[20];
            #pragma unroll
            for (int k = 0; k < 5; k++) sq += 2.f * d[15 + k] * H1[k];
            int p = 0;
            #pragma unroll
            for (int k = 0; k < 5; k++) {
                #pragma unroll
                for (int k2 = k; k2 < 5; k2++) {
                    sq += ((k == k2) ? 1.f : 2.f) * d[p] * H2[p];
                    p++;
                }
            }
            A.sq[l] = sq;
        }
    }
}

// ---------------------------------------------------------------------------
// K3: scatter 4 segs (148) | bucket1 LDS-sort (256)
// ---------------------------------------------------------------------------
__global__ __launch_bounds__(256) void k3_fuseC(GA A)
{
    __shared__ float4 st4[CAP1];                   // 20KB
    __shared__ short  inv[CAP1];                   // 2.5KB
    __shared__ int h64[64], l64[64], c64[64];
    int B = blockIdx.x, t = threadIdx.x;

    if (B < A.sg.tstart[4]) {                      // ---- scatter ----
        int s = 0;
        while (s < 3 && B >= A.sg.tstart[s + 1]) s++;
        int i0 = (B - A.sg.tstart[s]) * 1024;
        const int* idx = A.sg.idx[s];
        int* cnt = A.sg.cnt[s];
        const int* rp = A.sg.rp[s];
        int* out = A.sg.out[s];
        int n = A.sg.n[s];
        #pragma unroll
        for (int j = 0; j < 4; j++) {
            int i = i0 + j * 256 + t;
            if (i < n) {
                int d = idx[i];
                int p = atomicSub(&cnt[d], 1) - 1;
                out[rp[d] + p] = i;
            }
        }
        return;
    }
    B -= A.sg.tstart[4];
    {                                              // ---- bucket1 ----
        int b = B;
        int n = A.bcnt1[b];
        if (n > CAP1) n = CAP1;
        size_t base = (size_t)b * CAP1;
        for (int j = t; j < n; j += 256) st4[j] = A.pay1[base + j];
        if (t < 64) h64[t] = 0;
        __syncthreads();
        for (int j = t; j < n; j += 256) {
            int rel = (int)(__float_as_uint(st4[j].x) >> 16) & 63;
            atomicAdd(&h64[rel], 1);
        }
        __syncthreads();
        if (t < 64) {                              // wave-level exclusive scan
            int v = h64[t];
            int val = v;
            #pragma unroll
            for (int d = 1; d < 64; d <<= 1) {
                int u = __shfl_up(val, d);
                if (t >= d) val += u;
            }
            l64[t] = val - v;
            c64[t] = val - v;
        }
        __syncthreads();
        for (int j = t; j < n; j += 256) {
            int rel = (int)(__float_as_uint(st4[j].x) >> 16) & 63;
            int p = atomicAdd(&c64[rel], 1);
            inv[p] = (short)j;
        }
        __syncthreads();
        int lo = A.bs1[b];
        for (int j = t; j < n; j += 256)           // coalesced sorted write
            A.rec1[lo + j] = st4[inv[j]];
        if (t < 64) A.rp1[(b << 6) + t] = lo + l64[t];
    }
}

// ---------------------------------------------------------------------------
// K4: pool0 (960)
// ---------------------------------------------------------------------------
__global__ __launch_bounds__(256) void k4_pool0(GA A)
{
    int gt = blockIdx.x * 256 + threadIdx.x;
    if (gt >= 16384 * 15) return;
    int c = gt / 15, o = gt - c * 15;
    int r0 = A.sg.rp[3][c], r1 = A.sg.rp[3][c + 1];
    const int* cnid = A.sg.out[3];
    int d = r1 - r0;
    if (o < 12) {
        float m = -INFINITY;
        for (int j = r0; j < r1; j++)
            m = fmaxf(m, A.y0[(size_t)cnid[j] * 12 + o]);
        if (d == 0 || !isfinite(m)) m = 0.f;
        A.xn0[c * 15 + o] = m;
    } else {
        int k = o - 12;
        float sum = 0.f;
        for (int j = r0; j < r1; j++)
            sum += A.pos0[cnid[j] * 3 + k];
        A.xn0[c * 15 + o] = sum / fmaxf((float)d, 1.f);
    }
}

// ---------------------------------------------------------------------------
// K5: conv1 (block/node, streams rec1, plain xn0 input) + pool->raw1
// ---------------------------------------------------------------------------
__global__ __launch_bounds__(256) void k5_conv1(GA A)
{
    constexpr int CI = 15, CO = 20, CH = 48, CICO = CI * CO, RN = 24;
    __shared__ float w1s[20];
    __shared__ float4 recb[CH];
    __shared__ int   svb[CH];
    __shared__ float hb[CH * 6];
    __shared__ float xs[CH * CI];
    __shared__ float Sx[6 * CI];
    __shared__ float xown[CI];

    int t = threadIdx.x, v = blockIdx.x;
    if (t < 20) w1s[t] = (t < 15) ? A.w1[1][t] : A.b1[1][t - 15];
    if (t < CI) xown[t] = A.xn0[v * CI + t];
    int r0 = A.rp1[v], r1 = A.rp1[v + 1];
    int d = r1 - r0;
    float acc = 0.f;

    for (int c0 = r0; c0 < r1; c0 += CH) {
        int cn = min(CH, r1 - c0);
        if (t < cn) {
            float4 R = A.rec1[c0 + t];
            recb[t] = R;
            svb[t]  = (int)(__float_as_uint(R.x) & 0xffffu);
            hb[t * 6] = 1.f;
        }
        __syncthreads();
        if (t < cn * 5) {
            int j = t / 5, k = t % 5;
            float e0 = recb[j].y, e1 = recb[j].z, e2 = recb[j].w;
            hb[j * 6 + 1 + k] =
                ftanh(e0 * w1s[k] + e1 * w1s[5 + k] + e2 * w1s[10 + k] + w1s[15 + k]);
        }
        for (int u = t; u < cn * CI; u += 256) {
            int j = u / CI, i = u - j * CI;
            xs[u] = A.xn0[svb[j] * CI + i];
        }
        __syncthreads();
        if (t < 6 * CI) {
            int i = t / 6, k6 = t - (t / 6) * 6;
            for (int j = 0; j < cn; j++)
                acc += hb[j * 6 + k6] * xs[j * CI + i];
        }
        __syncthreads();
    }

    if (t < 6 * CI) Sx[t] = acc;
    __syncthreads();

    if (t < CO) {
        float m = 0.f;
        const float* w2 = A.w2[1];
        const float* b2 = A.b2[1];
        for (int i = 0; i < CI; i++) {
            m += b2[i * CO + t] * Sx[i * 6];
            #pragma unroll
            for (int k = 0; k < 5; k++)
                m += w2[k * CICO + i * CO + t] * Sx[i * 6 + 1 + k];
        }
        m /= fmaxf((float)d, 1.f);
        for (int i = 0; i < CI; i++) m += xown[i] * A.root[1][i * CO + t];
        m += A.bias[1][t];
        int c = A.cluster[1][v];
        unsigned* orow = A.raw[1] + (size_t)c * RN;
        atomicMax(&orow[t], fenc(m));
        if (t < 3) atomicAdd((float*)&orow[CO + t], xown[CI - 3 + t]);
        if (t == 0) atomicAdd((float*)&orow[CO + 3], 1.f);
    }
}

// ---------------------------------------------------------------------------
// K6-8: coop conv levels 2-4 + fused pool epilogue
// ---------------------------------------------------------------------------
template<int CI, int CO>
__global__ __launch_bounds__(256) void coopP_k(GA A, int l)
{
    constexpr int CH = 48, CICO = CI * CO, RL = CI + 1, RN = CO + 4;
    __shared__ float w1s[20];
    __shared__ int   eb[CH], svb[CH];
    __shared__ float hb[CH * 6];
    __shared__ float xs[CH * CI];
    __shared__ float Sx[6 * CI];
    __shared__ float xown[CI];

    int t = threadIdx.x, v = blockIdx.x;
    int s = l - 2;
    const unsigned* rin = A.raw[l - 1];
    const int* rp = A.sg.rp[s];
    const int* eid = A.sg.out[s];
    const int* src = A.srcE[s];
    const float* eattr = A.eaE[s];

    if (t < 20) w1s[t] = (t < 15) ? A.w1[l][t] : A.b1[l][t - 15];
    if (t < CI) xown[t] = row_val(rin + (size_t)v * RL, t, CI);
    int r0 = rp[v], r1 = rp[v + 1];
    int d = r1 - r0;
    float acc = 0.f;

    for (int c0 = r0; c0 < r1; c0 += CH) {
        int cn = min(CH, r1 - c0);
        if (t < cn) {
            int e = eid[c0 + t];
            eb[t]  = e;
            svb[t] = src[e];
            hb[t * 6] = 1.f;
        }
        __syncthreads();
        if (t < cn * 5) {
            int j = t / 5, k = t % 5;
            int e = eb[j];
            float e0 = eattr[e * 3], e1 = eattr[e * 3 + 1], e2 = eattr[e * 3 + 2];
            hb[j * 6 + 1 + k] =
                ftanh(e0 * w1s[k] + e1 * w1s[5 + k] + e2 * w1s[10 + k] + w1s[15 + k]);
        }
        for (int u = t; u < cn * CI; u += 256) {
            int j = u / CI, i = u - j * CI;
            xs[u] = row_val(rin + (size_t)svb[j] * RL, i, CI);
        }
        __syncthreads();
        if (t < 6 * CI) {
            int i = t / 6, k6 = t - (t / 6) * 6;
            for (int j = 0; j < cn; j++)
                acc += hb[j * 6 + k6] * xs[j * CI + i];
        }
        __syncthreads();
    }

    if (t < 6 * CI) Sx[t] = acc;
    __syncthreads();

    if (t < CO) {
        float m = 0.f;
        const float* w2 = A.w2[l];
        const float* b2 = A.b2[l];
        for (int i = 0; i < CI; i++) {
            m += b2[i * CO + t] * Sx[i * 6];
            #pragma unroll
            for (int k = 0; k < 5; k++)
                m += w2[k * CICO + i * CO + t] * Sx[i * 6 + 1 + k];
        }
        m /= fmaxf((float)d, 1.f);
        for (int i = 0; i < CI; i++) m += xown[i] * A.root[l][i * CO + t];
        m += A.bias[l][t];
        int c = A.cluster[l][v];
        unsigned* orow = A.raw[l] + (size_t)c * RN;
        atomicMax(&orow[t], fenc(m));
        if (t < 3) atomicAdd((float*)&orow[CO + t], xown[CI - 3 + t]);
        if (t == 0) atomicAdd((float*)&orow[CO + 3], 1.f);
    }
}

// ---------------------------------------------------------------------------
// K9: fc (decodes raw[4])
// ---------------------------------------------------------------------------
__global__ __launch_bounds__(128) void k9_fc(GA A)
{
    __shared__ float feat[8 * 376];
    __shared__ float logit[80];
    __shared__ float roff[8];
    const unsigned* r5 = A.raw[4];
    for (int idx = threadIdx.x; idx < 64 * 47; idx += 128) {
        int n = idx / 47, i = idx - n * 47;
        int b = n >> 3, s = n & 7;
        feat[b * 376 + s * 47 + i] = row_val(r5 + (size_t)n * 48, i, 47);
    }
    __syncthreads();
    int t = threadIdx.x;
    if (t < 80) {
        int b = t / 10, j = t % 10;
        float acc = A.fc_b[j];
        for (int k = 0; k < 376; k++) acc += feat[b * 376 + k] * A.fc_w[k * 10 + j];
        logit[t] = acc;
    }
    __syncthreads();
    if (t < 8) {
        float m = -1e30f;
        for (int j = 0; j < 10; j++) m = fmaxf(m, logit[t * 10 + j]);
        float ssum = 0.f;
        for (int j = 0; j < 10; j++) ssum += expf(logit[t * 10 + j] - m);
        roff[t] = m + logf(ssum);
    }
    __syncthreads();
    if (t < 80) A.out[t] = logit[t] - roff[t / 10];
    if (t == 0) {
        const float* sq = A.sq;
        float closs = 0.f;
        closs += sq[0] * (1.0f / 12582912.0f);
        closs += sq[1] * (1.0f / 78643200.0f);
        closs += sq[2] * (1.0f / 42205184.0f);
        closs += sq[3] * (1.0f / 18284544.0f);
        closs += sq[4] * (1.0f / 7028736.0f);
        A.out[80] = closs;
    }
}

// ---------------------------------------------------------------------------

extern "C" void kernel_launch(void* const* d_in, const int* in_sizes, int n_in,
                              void* d_out, int out_size, void* d_ws, size_t ws_size,
                              hipStream_t stream)
{
    static const int NSa[6] = {65536, 16384, 4096, 1024, 256, 64};
    static const int ESa[5] = {1048576, 262144, 65536, 16384, 4096};
    static const int RNa[5] = {16, 24, 32, 40, 48};   // raw row widths (words)

    // ---- workspace layout (words) ----
    int* wsw = (int*)d_ws;
    size_t off = 0;
    auto alw = [&](size_t n) -> size_t {
        size_t p = off; off += (n + 63) & ~(size_t)63; return p;
    };
    // zeroed region
    size_t degO[5];
    for (int l = 2; l < 5; l++) degO[l] = alw(NSa[l]);
    size_t cdeg0O = alw(NSa[1]);                      // cluster0 counts
    size_t HO    = alw(100);
    size_t bcO   = alw(NBK0);
    size_t bc1O  = alw(NBK1);
    size_t rawO[5];
    for (int l = 1; l < 5; l++) rawO[l] = alw((size_t)NSa[l + 1] * RNa[l]);
    size_t zeroWords = off;
    // non-zeroed
    size_t rpO[5], eidO[5];
    for (int l = 2; l < 5; l++) rpO[l]  = alw(NSa[l] + 1);
    size_t crp0O = alw(NSa[1] + 1);
    for (int l = 2; l < 5; l++) eidO[l] = alw(ESa[l]);
    size_t cnid0O = alw(NSa[0]);
    size_t pay2O = alw((size_t)NBK0 * CAP0 * 4);
    size_t y0O   = alw((size_t)NSa[0] * 12);
    size_t xn0O  = alw((size_t)NSa[1] * 15);
    size_t bs1O  = alw(NBK1 + 1);
    size_t pay1O = alw((size_t)NBK1 * CAP1 * 4);
    size_t rec1O = alw((size_t)ESa[1] * 4);
    size_t rp1O  = alw(NSa[1] + 1);
    size_t sqO   = alw(8);

    GA A{};
    A.src0 = (const int*)d_in[2];  A.dst0 = (const int*)d_in[3];
    A.ea0  = (const float*)d_in[4];
    A.src1 = (const int*)d_in[12]; A.dst1 = (const int*)d_in[13];
    A.ea1  = (const float*)d_in[14];
    A.x0   = (const float*)d_in[0];
    A.pos0 = (const float*)d_in[1];
    for (int l = 0; l < 5; l++) {
        A.cluster[l] = (const int*)d_in[5 + 10 * l];
        A.w1[l]   = (const float*)d_in[6 + 10 * l];
        A.b1[l]   = (const float*)d_in[7 + 10 * l];
        A.w2[l]   = (const float*)d_in[8 + 10 * l];
        A.b2[l]   = (const float*)d_in[9 + 10 * l];
        A.root[l] = (const float*)d_in[10 + 10 * l];
        A.bias[l] = (const float*)d_in[11 + 10 * l];
    }
    for (int s = 0; s < 3; s++) {
        A.srcE[s] = (const int*)d_in[2 + 10 * (s + 2)];
        A.eaE[s]  = (const float*)d_in[4 + 10 * (s + 2)];
    }
    A.fc_w = (const float*)d_in[52];
    A.fc_b = (const float*)d_in[53];
    A.bcnt  = wsw + bcO;
    A.bcnt1 = wsw + bc1O;
    A.pay2 = (float4*)(wsw + pay2O);
    A.pay1 = (float4*)(wsw + pay1O);
    A.rec1 = (float4*)(wsw + rec1O);
    A.y0   = (float*)(wsw + y0O);
    A.xn0  = (float*)(wsw + xn0O);
    for (int l = 1; l < 5; l++) A.raw[l] = (unsigned*)(wsw + rawO[l]);
    A.H  = (float*)(wsw + HO);
    A.sq = (float*)(wsw + sqO);
    A.bs1 = wsw + bs1O;
    A.rp1 = wsw + rp1O;
    A.out = (float*)d_out;

    // seg descriptors: 0-2 = edge segs L2-4, 3 = cluster0
    int tiles = 0;
    for (int s = 0; s < 3; s++) {
        int l = s + 2;
        A.sg.idx[s] = (const int*)d_in[3 + 10 * l];
        A.sg.cnt[s] = wsw + degO[l];
        A.sg.rp [s] = wsw + rpO[l];
        A.sg.out[s] = wsw + eidO[l];
        A.sg.n  [s] = ESa[l];
        A.sg.nb [s] = NSa[l];
        A.sg.tstart[s] = tiles;
        tiles += (ESa[l] + 1023) / 1024;
    }
    A.sg.idx[3] = (const int*)d_in[5];              // cluster0
    A.sg.cnt[3] = wsw + cdeg0O;
    A.sg.rp [3] = wsw + crp0O;
    A.sg.out[3] = wsw + cnid0O;
    A.sg.n  [3] = NSa[0];
    A.sg.nb [3] = NSa[1];
    A.sg.tstart[3] = tiles;
    tiles += (NSa[0] + 1023) / 1024;
    A.sg.tstart[4] = tiles;                          // 148

    int hsB = 0;
    A.hb0[0] = 0;
    for (int j = 0; j < 3; j++) {                    // hstats: levels 2-4
        hsB += (ESa[j + 2] + 2047) / 2048;
        A.hb0[j + 1] = hsB;
    }
    A.hsB = hsB;                                     // 42

    hipMemsetAsync(d_ws, 0, zeroWords * 4, stream);

    k1_fuseA<<<NT0 + NT1 + hsB + tiles, 256, 0, stream>>>(A);   // 830
    k2_fuseB<<<NBK0 + 1 + 3 + 1 + 5,    256, 0, stream>>>(A);   // 266
    k3_fuseC<<<tiles + NBK1,            256, 0, stream>>>(A);   // 404
    k4_pool0<<<(16384 * 15 + 255) / 256, 256, 0, stream>>>(A);  // 960
    k5_conv1<<<NSa[1],                  256, 0, stream>>>(A);   // 16384
    coopP_k<23, 28><<<NSa[2],           256, 0, stream>>>(A, 2);
    coopP_k<31, 36><<<NSa[3],           256, 0, stream>>>(A, 3);
    coopP_k<39, 44><<<NSa[4],           256, 0, stream>>>(A, 4);
    k9_fc<<<1, 128, 0, stream>>>(A);
}